// Round 12
// baseline (3253.800 us; speedup 1.0000x reference)
//
#include <hip/hip_runtime.h>
#include <cstdint>
#include <cstddef>

#define NB 4096
#define NN 64
#define LDP 68   // LDS stride: 272B = 16B-aligned, spreads lanes over bank-quads
#define LD2 65   // single-block kernels: LDS stride (scalar access, conflict-free)

// ---- workspace float offsets ----
#define OFF_MEAN  0
#define OFF_MS    4096
#define OFF_MIS   8192
#define OFF_LINV  12288
#define OFF_LB    16384
#define OFF_VAR   20480
#define OFF_SLOTS 24576
#define NSLOTS    32
#define OFF_C     (OFF_SLOTS + NSLOTS*4096)        // 155648 (C = Linv*Ms)
#define WS_ZERO_FLOATS (OFF_SLOTS + NSLOTS*4096)   // zero slots+var region
#define OFF_Q     286720                            // keep legacy layout
#define OFF_LAM   (OFF_Q + (size_t)NB*4096)
#define WS_FULL   (OFF_LAM + (size_t)NB*64)

typedef float f32x4 __attribute__((ext_vector_type(4)));

__device__ __forceinline__ float bperm(int pad, float v){
  return __int_as_float(__builtin_amdgcn_ds_bpermute(pad, __float_as_int(v)));
}

// =====================================================================
// One-sided Jacobi with LDS master copy (col-major, stride LDP).
// KEY FIX vs R8/R10: partner column is read via VOLATILE f32x4 loads.
// Volatile accesses cannot be duplicated/rematerialized by the compiler
// (R4 "+v" pins and R8 memory-clobber both failed: plain loads may be
// legally re-executed, and the compiler re-read all 16 b128 in the
// rotate pass, making a rotating round 48 DS ops instead of 32 --
// R10 counters: DS pipe ~90% saturated incl. remat). With volatile,
// rotating round = 16 reads + 16 writes; skip round = 16 reads.
// Rotation threshold is scale-invariant. nrm tracked analytically,
// exact recompute at end. All ops intra-wave.
// =====================================================================
__device__ __forceinline__ void jacobi64_lds(float col[64], float& nrm,
                                             float* __restrict__ Wm,
                                             const int t,
                                             const int maxsweep, const float tolsq) {
  {
#pragma unroll
    for (int jb=0;jb<16;jb++)
      *reinterpret_cast<f32x4*>(Wm + t*LDP + 4*jb) =
        (f32x4){col[4*jb],col[4*jb+1],col[4*jb+2],col[4*jb+3]};
    float n0=0.f,n1=0.f,n2=0.f,n3=0.f;
#pragma unroll
    for (int j=0;j<64;j+=4){
      n0=fmaf(col[j+0],col[j+0],n0); n1=fmaf(col[j+1],col[j+1],n1);
      n2=fmaf(col[j+2],col[j+2],n2); n3=fmaf(col[j+3],col[j+3],n3);
    }
    nrm=(n0+n1)+(n2+n3);
  }
#pragma unroll 1
  for (int sw=0; sw<maxsweep; ++sw){
    int anyrot=0;
#pragma unroll 1
    for (int m=1; m<64; ++m){
      const int pad = ((t ^ m) << 2);
      const volatile f32x4* P =
        reinterpret_cast<const volatile f32x4*>(Wm + (t ^ m)*LDP);
      float pn = bperm(pad, nrm);
      // partner column: 16 volatile b128 loads -> MUST stay in VGPRs
      f32x4 q[16];
#pragma unroll
      for (int jb=0;jb<16;jb++) q[jb] = P[jb];
      float a0=0.f,a1=0.f,a2=0.f,a3=0.f;
#pragma unroll
      for (int jb=0;jb<16;jb++){
        a0=fmaf(col[4*jb+0],q[jb][0],a0); a1=fmaf(col[4*jb+1],q[jb][1],a1);
        a2=fmaf(col[4*jb+2],q[jb][2],a2); a3=fmaf(col[4*jb+3],q[jb][3],a3);
      }
      float apq=(a0+a1)+(a2+a3);
      const bool isP = t < (t ^ m);
      float app = isP ? nrm : pn;
      float aqq = isP ? pn : nrm;
      const bool rot = (apq*apq > tolsq*app*aqq);
      if (__any((int)rot)){
        float tau = (aqq - app) / (2.0f*apq);
        float tt  = 1.0f / (fabsf(tau) + sqrtf(fmaf(tau,tau,1.0f)));
        tt = (tau < 0.0f) ? -tt : tt;
        float cc = rsqrtf(fmaf(tt,tt,1.0f));
        float ss = cc*tt;
        float ccv = rot ? cc : 1.0f;
        float sgv = rot ? (isP ? -ss : ss) : 0.0f;
#pragma unroll
        for (int jb=0;jb<16;jb++){
          col[4*jb+0]=fmaf(ccv,col[4*jb+0],sgv*q[jb][0]);
          col[4*jb+1]=fmaf(ccv,col[4*jb+1],sgv*q[jb][1]);
          col[4*jb+2]=fmaf(ccv,col[4*jb+2],sgv*q[jb][2]);
          col[4*jb+3]=fmaf(ccv,col[4*jb+3],sgv*q[jb][3]);
        }
        float tq = tt*apq;
        nrm += rot ? (isP ? -tq : tq) : 0.0f;
        if (rot){
#pragma unroll
          for (int jb=0;jb<16;jb++)
            *reinterpret_cast<f32x4*>(Wm + t*LDP + 4*jb) =
              (f32x4){col[4*jb],col[4*jb+1],col[4*jb+2],col[4*jb+3]};
        }
        anyrot = 1;
      }
    }
    if (!__any(anyrot)) break;
  }
  {
    float n0=0.f,n1=0.f,n2=0.f,n3=0.f;
#pragma unroll
    for (int j=0;j<64;j+=4){
      n0=fmaf(col[j+0],col[j+0],n0); n1=fmaf(col[j+1],col[j+1],n1);
      n2=fmaf(col[j+2],col[j+2],n2); n3=fmaf(col[j+3],col[j+3],n3);
    }
    nrm=(n0+n1)+(n2+n3);
  }
}

// =====================================================================
// LDS-free congruence: col = (M * Xb * M^T) column t = M * (Xb * m_t).
// =====================================================================
__device__ __forceinline__ void cong_cols(const float* __restrict__ Xb,
                                          const float* __restrict__ M,
                                          float col[64], const int t){
  float mrow[64];
#pragma unroll
  for (int j=0;j<16;j++){
    float4 v = *reinterpret_cast<const float4*>(M + t*64 + 4*j);
    mrow[4*j+0]=v.x; mrow[4*j+1]=v.y; mrow[4*j+2]=v.z; mrow[4*j+3]=v.w;
  }
#pragma unroll
  for (int i=0;i<64;i++) col[i]=0.f;
#pragma unroll 1
  for (int kb=0;kb<16;kb++){
    const float* xr = Xb + kb*256;
    float z0=0.f,z1=0.f,z2=0.f,z3=0.f;
#pragma unroll
    for (int j=0;j<64;j++){
      float mj = mrow[j];
      z0 = fmaf(xr[      j], mj, z0);
      z1 = fmaf(xr[ 64 + j], mj, z1);
      z2 = fmaf(xr[128 + j], mj, z2);
      z3 = fmaf(xr[192 + j], mj, z3);
    }
    const float* mc = M + 4*kb;
#pragma unroll
    for (int i=0;i<64;i++){
      float c = col[i];
      c = fmaf(mc[i*64+0], z0, c);
      c = fmaf(mc[i*64+1], z1, c);
      c = fmaf(mc[i*64+2], z2, c);
      c = fmaf(mc[i*64+3], z3, c);
      col[i] = c;
    }
  }
}

// ================= K1: batch mean =================
__global__ __launch_bounds__(256) void k_mean(const float* __restrict__ X, float* __restrict__ meanAcc){
  const int tid=threadIdx.x; const int blk=blockIdx.x;
  float acc[16];
#pragma unroll
  for (int j=0;j<16;j++) acc[j]=0.f;
  const float* p = X + (size_t)blk*32*4096;
  for (int b2=0;b2<32;b2++){
#pragma unroll
    for (int j=0;j<16;j++) acc[j] += p[(size_t)b2*4096 + tid + 256*j];
  }
#pragma unroll
  for (int j=0;j<16;j++) atomicAdd(&meanAcc[tid+256*j], acc[j]*(1.0f/4096.0f));
}

// ================= 256-thread LDS matmul (col-major, stride LD2) =================
template<int MODE>
__device__ __forceinline__ void mmc256(float* __restrict__ dst, const float* __restrict__ A,
                                       const float* __restrict__ B, const float p0){
  const int tid=threadIdx.x; const int t=tid&63; const int i0=(tid>>6)*16;
  float acc[16];
#pragma unroll
  for (int j=0;j<16;j++) acc[j]=0.f;
#pragma unroll 4
  for (int k=0;k<64;k++){
    float bk = B[t*LD2+k];
#pragma unroll
    for (int j=0;j<16;j++) acc[j] = fmaf(A[k*LD2+i0+j], bk, acc[j]);
  }
  __syncthreads();
#pragma unroll
  for (int j=0;j<16;j++){
    int i=i0+j;
    float v=acc[j];
    if (MODE==1) v*=0.5f;
    if (MODE==2) v = ((i==t)?3.0f:0.0f) - v;
    if (MODE==3) v = v + ((i==t)?p0:0.0f);
    dst[t*LD2+i]=v;
  }
  __syncthreads();
}

__device__ __forceinline__ void chol_lds(float* __restrict__ C, const int tid, const int t, const int g){
  for (int j=0;j<64;j++){
    if (tid<64){
      float ljj = sqrtf(C[j*LD2+j]);
      float rinv = 1.0f/ljj;
      if (tid>=j) C[j*LD2+tid] = (tid==j)? ljj : C[j*LD2+tid]*rinv;
    }
    __syncthreads();
    for (int c=j+1+g; c<64; c+=4){
      float ljc = C[j*LD2+c];
      if (t>=c) C[c*LD2+t] -= C[j*LD2+t]*ljc;
    }
    __syncthreads();
  }
}

// ================= K2: Ms = mean^{1/2}, Mis = mean^{-1/2} via Newton-Schulz ====
__global__ __launch_bounds__(256) void k_sqrtmean(const float* __restrict__ meanw,
                                                  float* __restrict__ Msg, float* __restrict__ Misg){
  __shared__ float bufY[64*LD2], bufZ[64*LD2], bufT[64*LD2];
  const int tid=threadIdx.x;
  float tr=0.f;
  for (int k=0;k<64;k++) tr += meanw[k*65];
  const float alpha = 64.0f/tr;
  for (int e=tid; e<4096; e+=256){
    int r=e>>6, c=e&63;
    bufY[c*LD2+r] = alpha*meanw[e];
    bufZ[c*LD2+r] = (r==c)?1.0f:0.0f;
  }
  __syncthreads();
  float *pY=bufY, *pZ=bufZ, *pT=bufT;
  for (int it=0; it<5; ++it){
    mmc256<2>(pT, pZ, pY, 0.f);   // T = 3I - Z*Y
    mmc256<1>(pZ, pT, pZ, 0.f);   // Z' = 0.5*T*Z
    mmc256<1>(pT, pY, pT, 0.f);   // Y' = 0.5*Y*T
    float* tm=pY; pY=pT; pT=tm;
  }
  const float sa = sqrtf(alpha);
  const float isa = 1.0f/sa;
  for (int e=tid; e<4096; e+=256){
    int r=e>>6, c=e&63;
    Msg[e]  = pY[c*LD2+r]*isa;
    Misg[e] = pZ[c*LD2+r]*sa;
  }
}

// ================= K3: accumulate log(Mis X Mis) into slots =================
// Phase-1 = R10-PASSING config (1e-8, 7). The rescaled warm start
// (W Lam^{-1/2}) requires phase-1 convergence: its residual enters Xc
// undamped (R9 failed at (1e-6,5)). R11 confirmed the rescale is
// REQUIRED: one-sided Jacobi's invariant is W W^T = A^2, so the
// unnormalized W0=C*W feeds phase-2 the eigensystem of C A^2 C^T.
template<bool STOREQ>
__global__ __launch_bounds__(64,2) void k_logaccum(const float* __restrict__ X,
                                                   const float* __restrict__ Mis,
                                                   float* __restrict__ slots,
                                                   float* __restrict__ Qs,
                                                   float* __restrict__ Ls){
  __shared__ __align__(16) float Wm[64*LDP];
  __shared__ float wcoef[64];
  const int t=threadIdx.x & 63; const int b=blockIdx.x;
  float col[64]; float nrm;
  cong_cols(X + (size_t)b*4096, Mis, col, t);
  jacobi64_lds(col, nrm, Wm, t, 7, 1e-8f);
  if (STOREQ){
#pragma unroll
    for (int j=0;j<16;j++)
      *reinterpret_cast<float4*>(Qs + (size_t)b*4096 + t*64 + 4*j) =
          make_float4(col[4*j],col[4*j+1],col[4*j+2],col[4*j+3]);
    Ls[(size_t)b*64+t] = nrm;
  }
  wcoef[t] = 0.5f*logf(nrm)/nrm;
  float acc[64];
#pragma unroll
  for (int i=0;i<64;i++) acc[i]=0.f;
#pragma unroll 1
  for (int k=0;k<64;k++){
    float f = wcoef[k]*Wm[k*LDP+t];
#pragma unroll
    for (int jj=0;jj<16;jj++){
      float4 a = *reinterpret_cast<const float4*>(&Wm[k*LDP+4*jj]);
      acc[4*jj+0]=fmaf(a.x,f,acc[4*jj+0]); acc[4*jj+1]=fmaf(a.y,f,acc[4*jj+1]);
      acc[4*jj+2]=fmaf(a.z,f,acc[4*jj+2]); acc[4*jj+3]=fmaf(a.w,f,acc[4*jj+3]);
    }
  }
  float* dst = slots + (size_t)(b & (NSLOTS-1))*4096;
#pragma unroll
  for (int i=0;i<64;i++) atomicAdd(&dst[i*64+t], acc[i]);
}

// ================= K4: exp(tang), batch_mean, chol, Linv, Lb, C=Linv*Ms ======
__global__ __launch_bounds__(256) void k_mid(const float* __restrict__ slots,
                                             const float* __restrict__ Msg,
                                             const float* __restrict__ bias,
                                             float* __restrict__ Linvg, float* __restrict__ Lbg,
                                             float* __restrict__ Cg){
  __shared__ float b1[64*LD2], b2[64*LD2], b3[64*LD2];
  const int tid=threadIdx.x; const int t=tid&63; const int g=tid>>6;
  for (int e=tid; e<4096; e+=256){
    float s=0.f;
    for (int sl=0; sl<NSLOTS; ++sl) s += slots[(size_t)sl*4096+e];
    b1[(e&63)*LD2+(e>>6)] = s * (1.0f/(4096.0f*16.0f));
  }
  __syncthreads();
  for (int e=tid; e<4096; e+=256){
    int r=e>>6, c=e&63;
    b2[c*LD2+r] = (1.0f/40320.0f)*b1[c*LD2+r] + ((r==c)?(1.0f/5040.0f):0.0f);
  }
  __syncthreads();
  float *pR=b2, *pT=b3;
  const float cj0=1.f/720.f, cj1=1.f/120.f, cj2=1.f/24.f, cj3=1.f/6.f, cj4=0.5f, cj5=1.f, cj6=1.f;
  mmc256<3>(pT,b1,pR,cj0); { float* tm=pR; pR=pT; pT=tm; }
  mmc256<3>(pT,b1,pR,cj1); { float* tm=pR; pR=pT; pT=tm; }
  mmc256<3>(pT,b1,pR,cj2); { float* tm=pR; pR=pT; pT=tm; }
  mmc256<3>(pT,b1,pR,cj3); { float* tm=pR; pR=pT; pT=tm; }
  mmc256<3>(pT,b1,pR,cj4); { float* tm=pR; pR=pT; pT=tm; }
  mmc256<3>(pT,b1,pR,cj5); { float* tm=pR; pR=pT; pT=tm; }
  mmc256<3>(pT,b1,pR,cj6); { float* tm=pR; pR=pT; pT=tm; }
  for (int q=0;q<4;q++){ mmc256<0>(pT, pR, pR, 0.f); float* tm=pR; pR=pT; pT=tm; }
  for (int e=tid; e<4096; e+=256) b1[(e&63)*LD2+(e>>6)] = Msg[e];
  __syncthreads();
  mmc256<0>(pT, b1, pR, 0.f);   // T = Ms*E
  mmc256<0>(pR, pT, b1, 0.f);   // bm = T*Ms
  chol_lds(pR, tid, t, g);      // pR holds L (lower, col-major)
  if (tid<64){
    const int c=tid;
    for (int k=0;k<64;k++) pT[c*LD2+k]=0.f;
    for (int i=0;i<64;i++){
      float s = (i==c)?1.0f:0.0f;
      for (int k=0;k<i;k++) s -= pR[k*LD2+i]*pT[c*LD2+k];
      pT[c*LD2+i] = s / pR[i*LD2+i];
    }
  }
  __syncthreads();
  if (tid<64){
    const int c=tid;
    for (int i=0;i<64;i++) Linvg[i*64+c] = pT[c*LD2+i];
  }
  // C = Linv * Ms  (pT holds Linv col-major, b1 holds Ms col-major)
  mmc256<0>(pR, pT, b1, 0.f);   // pR[t*LD2+i] = C[i][t]
  for (int e=tid; e<4096; e+=256) Cg[e] = pR[(e&63)*LD2+(e>>6)];  // row-major
  for (int e=tid; e<4096; e+=256) b1[(e&63)*LD2+(e>>6)] = bias[e];
  __syncthreads();
  chol_lds(b1, tid, t, g);
  if (tid<64){
    const int c=tid;
    for (int i=0;i<64;i++) Lbg[i*64+c] = (c<=i)? b1[c*LD2+i] : 0.0f;
  }
}

// ================= K5: Xc eig via warm start, var accumulation =================
// WARM: W0 col t = C * (lam_t^{-1/2} w_t)  (w = phase-1 col, nrm = lam^2).
// W0 W0^T = C (W Lam^{-1} W^T) C^T = C A_b C^T = Xc up to phase-1 residual
// (small at (1e-8,7)). Off-diag of W0^T W0 ~ ||tang|| ~ 0.03 -> ~3-4 sweeps.
template<bool WARM>
__global__ __launch_bounds__(64,2) void k_center(const float* __restrict__ X,
                                                 const float* __restrict__ Linv,
                                                 const float* __restrict__ Cg,
                                                 float* __restrict__ varAcc,
                                                 float* __restrict__ Qs, float* __restrict__ Ls){
  __shared__ __align__(16) float Wm[64*LDP];
  const int t=threadIdx.x & 63; const int b=blockIdx.x;
  float col[64]; float nrm;
  if (WARM){
    const float s = rsqrtf(sqrtf(Ls[(size_t)b*64+t]));   // lam^{-1/2} (nrm=lam^2)
    const float* q1 = Qs + (size_t)b*4096 + t*64;
#pragma unroll
    for (int i=0;i<64;i++) col[i]=0.f;
#pragma unroll 1
    for (int kb=0;kb<16;kb++){
      float4 v = *reinterpret_cast<const float4*>(q1 + 4*kb);
      float x0=v.x*s, x1=v.y*s, x2=v.z*s, x3=v.w*s;
      const float* cc = Cg + 4*kb;
#pragma unroll
      for (int i=0;i<64;i++){
        float c = col[i];
        c = fmaf(cc[i*64+0], x0, c);
        c = fmaf(cc[i*64+1], x1, c);
        c = fmaf(cc[i*64+2], x2, c);
        c = fmaf(cc[i*64+3], x3, c);
        col[i] = c;
      }
    }
    jacobi64_lds(col, nrm, Wm, t, 8, 1e-10f);
  } else {
    cong_cols(X + (size_t)b*4096, Linv, col, t);
    jacobi64_lds(col, nrm, Wm, t, 10, 1e-10f);
  }
  float ll = 0.5f*logf(nrm);
  float f2 = ll*ll;
#pragma unroll
  for (int off=1; off<64; off<<=1) f2 += __shfl_xor(f2, off, 64);
  if (t==0) atomicAdd(varAcc, f2);
  if (WARM){
#pragma unroll
    for (int j=0;j<16;j++)
      *reinterpret_cast<float4*>(Qs + (size_t)b*4096 + t*64 + 4*j) =
          make_float4(col[4*j],col[4*j+1],col[4*j+2],col[4*j+3]);
    Ls[(size_t)b*64+t] = nrm;
  }
}

// ================= K7: Xs = sum lam^f q q^T ; out = Lb Xs Lb^T =================
template<bool LOADW>
__global__ __launch_bounds__(64,2) void k_out(const float* __restrict__ X,
                                              const float* __restrict__ Linv,
                                              const float* __restrict__ Qs,
                                              const float* __restrict__ Ls,
                                              const float* __restrict__ Lb,
                                              const float* __restrict__ varAcc,
                                              const float* __restrict__ shift,
                                              float* __restrict__ out){
  __shared__ __align__(16) float Wm[64*LDP];
  __shared__ float wcoef[64];
  const int t=threadIdx.x & 63; const int b=blockIdx.x;
  float col[64]; float nrm;
  if (LOADW){
#pragma unroll
    for (int j=0;j<16;j++){
      float4 v = *reinterpret_cast<const float4*>(Qs + (size_t)b*4096 + t*64 + 4*j);
      col[4*j+0]=v.x; col[4*j+1]=v.y; col[4*j+2]=v.z; col[4*j+3]=v.w;
    }
    nrm = Ls[(size_t)b*64+t];
#pragma unroll
    for (int j=0;j<16;j++)
      *reinterpret_cast<float4*>(&Wm[t*LDP+4*j]) = make_float4(col[4*j],col[4*j+1],col[4*j+2],col[4*j+3]);
  } else {
    cong_cols(X + (size_t)b*4096, Linv, col, t);
    jacobi64_lds(col, nrm, Wm, t, 10, 1e-10f);
  }
  const float var = varAcc[0] * (1.0f/4096.0f);
  const float factor = shift[0] * rsqrtf(var + 1e-5f);
  wcoef[t] = expf((factor-2.0f)*0.5f*logf(nrm));   // lam^{f-2}
  float acc[64];
#pragma unroll
  for (int i=0;i<64;i++) acc[i]=0.f;
#pragma unroll 1
  for (int k=0;k<64;k++){
    float f = wcoef[k]*Wm[k*LDP+t];
#pragma unroll
    for (int jj=0;jj<16;jj++){
      float4 a = *reinterpret_cast<const float4*>(&Wm[k*LDP+4*jj]);
      acc[4*jj+0]=fmaf(a.x,f,acc[4*jj+0]); acc[4*jj+1]=fmaf(a.y,f,acc[4*jj+1]);
      acc[4*jj+2]=fmaf(a.z,f,acc[4*jj+2]); acc[4*jj+3]=fmaf(a.w,f,acc[4*jj+3]);
    }
  }
  // T2 = Lb * Xs (single-wave block: all Wm reads above complete first)
#pragma unroll 2
  for (int i=0;i<64;i++){
    float s0=0.f,s1=0.f;
#pragma unroll
    for (int k=0;k<64;k+=2){ s0=fmaf(Lb[i*64+k],acc[k],s0); s1=fmaf(Lb[i*64+k+1],acc[k+1],s1); }
    Wm[t*LDP+i]=s0+s1;
  }
  float o[64];
#pragma unroll
  for (int i=0;i<64;i++) o[i]=0.f;
#pragma unroll 1
  for (int k=0;k<64;k++){
    float bk = Lb[t*64+k];
#pragma unroll
    for (int jj=0;jj<16;jj++){
      float4 a = *reinterpret_cast<const float4*>(&Wm[k*LDP+4*jj]);
      o[4*jj+0]=fmaf(a.x,bk,o[4*jj+0]); o[4*jj+1]=fmaf(a.y,bk,o[4*jj+1]);
      o[4*jj+2]=fmaf(a.z,bk,o[4*jj+2]); o[4*jj+3]=fmaf(a.w,bk,o[4*jj+3]);
    }
  }
  float* ob = out + (size_t)b*4096;
#pragma unroll
  for (int i=0;i<64;i++) ob[i*64+t] = o[i];
}

// =====================================================================
extern "C" void kernel_launch(void* const* d_in, const int* in_sizes, int n_in,
                              void* d_out, int out_size, void* d_ws, size_t ws_size,
                              hipStream_t stream){
  (void)in_sizes; (void)n_in; (void)out_size;
  const float* X     = (const float*)d_in[0];
  const float* bias  = (const float*)d_in[1];
  const float* shift = (const float*)d_in[2];
  float* out = (float*)d_out;
  float* ws  = (float*)d_ws;

  hipMemsetAsync(d_ws, 0, (size_t)WS_ZERO_FLOATS*sizeof(float), stream);
  k_mean<<<128,256,0,stream>>>(X, ws+OFF_MEAN);
  k_sqrtmean<<<1,256,0,stream>>>(ws+OFF_MEAN, ws+OFF_MS, ws+OFF_MIS);

  const bool big = ws_size >= (size_t)WS_FULL*sizeof(float);
  if (big){
    k_logaccum<true><<<NB,64,0,stream>>>(X, ws+OFF_MIS, ws+OFF_SLOTS, ws+OFF_Q, ws+OFF_LAM);
    k_mid<<<1,256,0,stream>>>(ws+OFF_SLOTS, ws+OFF_MS, bias, ws+OFF_LINV, ws+OFF_LB, ws+OFF_C);
    k_center<true><<<NB,64,0,stream>>>(X, ws+OFF_LINV, ws+OFF_C, ws+OFF_VAR, ws+OFF_Q, ws+OFF_LAM);
    k_out<true><<<NB,64,0,stream>>>(X, ws+OFF_LINV, ws+OFF_Q, ws+OFF_LAM, ws+OFF_LB, ws+OFF_VAR, shift, out);
  } else {
    k_logaccum<false><<<NB,64,0,stream>>>(X, ws+OFF_MIS, ws+OFF_SLOTS, nullptr, nullptr);
    k_mid<<<1,256,0,stream>>>(ws+OFF_SLOTS, ws+OFF_MS, bias, ws+OFF_LINV, ws+OFF_LB, ws+OFF_C);
    k_center<false><<<NB,64,0,stream>>>(X, ws+OFF_LINV, nullptr, ws+OFF_VAR, nullptr, nullptr);
    k_out<false><<<NB,64,0,stream>>>(X, ws+OFF_LINV, nullptr, nullptr, ws+OFF_LB, ws+OFF_VAR, shift, out);
  }
}

// Round 13
// 2936.578 us; speedup vs baseline: 1.1080x; 1.1080x over previous
//
#include <hip/hip_runtime.h>
#include <cstdint>
#include <cstddef>

#define NB 4096
#define NN 64
#define LDP 68   // LDS stride: 272B = 16B-aligned, spreads lanes over bank-quads
#define LD2 65   // single-block kernels: LDS stride (scalar access, conflict-free)

// ---- workspace float offsets ----
#define OFF_MEAN  0
#define OFF_MS    4096
#define OFF_MIS   8192
#define OFF_LINV  12288
#define OFF_LB    16384
#define OFF_VAR   20480
#define OFF_SLOTS 24576
#define NSLOTS    32
#define OFF_C     (OFF_SLOTS + NSLOTS*4096)        // 155648 (C = Linv*Ms)
#define WS_ZERO_FLOATS (OFF_SLOTS + NSLOTS*4096)   // zero slots+var region
#define OFF_Q     286720                            // keep legacy layout
#define OFF_LAM   (OFF_Q + (size_t)NB*4096)
#define WS_FULL   (OFF_LAM + (size_t)NB*64)

typedef float f32x4 __attribute__((ext_vector_type(4)));

__device__ __forceinline__ float bperm(int pad, float v){
  return __int_as_float(__builtin_amdgcn_ds_bpermute(pad, __float_as_int(v)));
}

// Generic LDS pointer -> 32-bit LDS byte address (shared aperture is
// 2^32-aligned, so truncation yields the DS offset).
__device__ __forceinline__ unsigned lds_addr(const void* p){
  return (unsigned)(unsigned long long)(uintptr_t)p;
}

// =====================================================================
// One-sided Jacobi with LDS master copy (col-major, stride LDP).
// Partner column fetched with 16 INLINE-ASM ds_read_b128:
//  - asm-defined regs cannot be rematerialized (kills the R7/R8/R10
//    re-read in the rotate pass: rotating round 48 -> ~33 DS ops),
//  - independent asm statements issue back-to-back (no volatile-style
//    serialization, the R12 failure),
//  - one manual s_waitcnt lgkmcnt(0), threaded through the q registers
//    as "+v" operands (rule #18) + sched_barrier(0),
//  - "memory" clobber on the first read of each round orders the
//    previous round's write-backs before it (DS is in-order per wave).
// Rotation threshold is scale-invariant. nrm tracked analytically,
// exact recompute at end. All ops intra-wave.
// =====================================================================
__device__ __forceinline__ void jacobi64_lds(float col[64], float& nrm,
                                             float* __restrict__ Wm,
                                             const int t,
                                             const int maxsweep, const float tolsq) {
  {
#pragma unroll
    for (int jb=0;jb<16;jb++)
      *reinterpret_cast<f32x4*>(Wm + t*LDP + 4*jb) =
        (f32x4){col[4*jb],col[4*jb+1],col[4*jb+2],col[4*jb+3]};
    float n0=0.f,n1=0.f,n2=0.f,n3=0.f;
#pragma unroll
    for (int j=0;j<64;j+=4){
      n0=fmaf(col[j+0],col[j+0],n0); n1=fmaf(col[j+1],col[j+1],n1);
      n2=fmaf(col[j+2],col[j+2],n2); n3=fmaf(col[j+3],col[j+3],n3);
    }
    nrm=(n0+n1)+(n2+n3);
  }
#pragma unroll 1
  for (int sw=0; sw<maxsweep; ++sw){
    int anyrot=0;
#pragma unroll 1
    for (int m=1; m<64; ++m){
      const int pad = ((t ^ m) << 2);
      const unsigned pbase = lds_addr(Wm + (t ^ m)*LDP);
      float pn = bperm(pad, nrm);
      f32x4 q0,q1,q2,q3,q4,q5,q6,q7,q8,q9,q10,q11,q12,q13,q14,q15;
      asm volatile("ds_read_b128 %0, %1"             : "=v"(q0)  : "v"(pbase) : "memory");
      asm volatile("ds_read_b128 %0, %1 offset:16"   : "=v"(q1)  : "v"(pbase));
      asm volatile("ds_read_b128 %0, %1 offset:32"   : "=v"(q2)  : "v"(pbase));
      asm volatile("ds_read_b128 %0, %1 offset:48"   : "=v"(q3)  : "v"(pbase));
      asm volatile("ds_read_b128 %0, %1 offset:64"   : "=v"(q4)  : "v"(pbase));
      asm volatile("ds_read_b128 %0, %1 offset:80"   : "=v"(q5)  : "v"(pbase));
      asm volatile("ds_read_b128 %0, %1 offset:96"   : "=v"(q6)  : "v"(pbase));
      asm volatile("ds_read_b128 %0, %1 offset:112"  : "=v"(q7)  : "v"(pbase));
      asm volatile("ds_read_b128 %0, %1 offset:128"  : "=v"(q8)  : "v"(pbase));
      asm volatile("ds_read_b128 %0, %1 offset:144"  : "=v"(q9)  : "v"(pbase));
      asm volatile("ds_read_b128 %0, %1 offset:160"  : "=v"(q10) : "v"(pbase));
      asm volatile("ds_read_b128 %0, %1 offset:176"  : "=v"(q11) : "v"(pbase));
      asm volatile("ds_read_b128 %0, %1 offset:192"  : "=v"(q12) : "v"(pbase));
      asm volatile("ds_read_b128 %0, %1 offset:208"  : "=v"(q13) : "v"(pbase));
      asm volatile("ds_read_b128 %0, %1 offset:224"  : "=v"(q14) : "v"(pbase));
      asm volatile("ds_read_b128 %0, %1 offset:240"  : "=v"(q15) : "v"(pbase));
      asm volatile("s_waitcnt lgkmcnt(0)"
        : "+v"(q0),"+v"(q1),"+v"(q2),"+v"(q3),"+v"(q4),"+v"(q5),"+v"(q6),"+v"(q7));
      asm volatile(""
        : "+v"(q8),"+v"(q9),"+v"(q10),"+v"(q11),"+v"(q12),"+v"(q13),"+v"(q14),"+v"(q15));
      __builtin_amdgcn_sched_barrier(0);
      float a0=0.f,a1=0.f,a2=0.f,a3=0.f;
#define DOT4(JB,Q) \
      a0=fmaf(col[4*JB+0],Q[0],a0); a1=fmaf(col[4*JB+1],Q[1],a1); \
      a2=fmaf(col[4*JB+2],Q[2],a2); a3=fmaf(col[4*JB+3],Q[3],a3);
      DOT4(0,q0) DOT4(1,q1) DOT4(2,q2) DOT4(3,q3)
      DOT4(4,q4) DOT4(5,q5) DOT4(6,q6) DOT4(7,q7)
      DOT4(8,q8) DOT4(9,q9) DOT4(10,q10) DOT4(11,q11)
      DOT4(12,q12) DOT4(13,q13) DOT4(14,q14) DOT4(15,q15)
#undef DOT4
      float apq=(a0+a1)+(a2+a3);
      const bool isP = t < (t ^ m);
      float app = isP ? nrm : pn;
      float aqq = isP ? pn : nrm;
      const bool rot = (apq*apq > tolsq*app*aqq);
      if (__any((int)rot)){
        float tau = (aqq - app) / (2.0f*apq);
        float tt  = 1.0f / (fabsf(tau) + sqrtf(fmaf(tau,tau,1.0f)));
        tt = (tau < 0.0f) ? -tt : tt;
        float cc = rsqrtf(fmaf(tt,tt,1.0f));
        float ss = cc*tt;
        float ccv = rot ? cc : 1.0f;
        float sgv = rot ? (isP ? -ss : ss) : 0.0f;
#define ROT4(JB,Q) \
        col[4*JB+0]=fmaf(ccv,col[4*JB+0],sgv*Q[0]); \
        col[4*JB+1]=fmaf(ccv,col[4*JB+1],sgv*Q[1]); \
        col[4*JB+2]=fmaf(ccv,col[4*JB+2],sgv*Q[2]); \
        col[4*JB+3]=fmaf(ccv,col[4*JB+3],sgv*Q[3]);
        ROT4(0,q0) ROT4(1,q1) ROT4(2,q2) ROT4(3,q3)
        ROT4(4,q4) ROT4(5,q5) ROT4(6,q6) ROT4(7,q7)
        ROT4(8,q8) ROT4(9,q9) ROT4(10,q10) ROT4(11,q11)
        ROT4(12,q12) ROT4(13,q13) ROT4(14,q14) ROT4(15,q15)
#undef ROT4
        float tq = tt*apq;
        nrm += rot ? (isP ? -tq : tq) : 0.0f;
        if (rot){
#pragma unroll
          for (int jb=0;jb<16;jb++)
            *reinterpret_cast<f32x4*>(Wm + t*LDP + 4*jb) =
              (f32x4){col[4*jb],col[4*jb+1],col[4*jb+2],col[4*jb+3]};
        }
        anyrot = 1;
      }
    }
    if (!__any(anyrot)) break;
  }
  {
    float n0=0.f,n1=0.f,n2=0.f,n3=0.f;
#pragma unroll
    for (int j=0;j<64;j+=4){
      n0=fmaf(col[j+0],col[j+0],n0); n1=fmaf(col[j+1],col[j+1],n1);
      n2=fmaf(col[j+2],col[j+2],n2); n3=fmaf(col[j+3],col[j+3],n3);
    }
    nrm=(n0+n1)+(n2+n3);
  }
}

// =====================================================================
// LDS-free congruence: col = (M * Xb * M^T) column t = M * (Xb * m_t).
// =====================================================================
__device__ __forceinline__ void cong_cols(const float* __restrict__ Xb,
                                          const float* __restrict__ M,
                                          float col[64], const int t){
  float mrow[64];
#pragma unroll
  for (int j=0;j<16;j++){
    float4 v = *reinterpret_cast<const float4*>(M + t*64 + 4*j);
    mrow[4*j+0]=v.x; mrow[4*j+1]=v.y; mrow[4*j+2]=v.z; mrow[4*j+3]=v.w;
  }
#pragma unroll
  for (int i=0;i<64;i++) col[i]=0.f;
#pragma unroll 1
  for (int kb=0;kb<16;kb++){
    const float* xr = Xb + kb*256;
    float z0=0.f,z1=0.f,z2=0.f,z3=0.f;
#pragma unroll
    for (int j=0;j<64;j++){
      float mj = mrow[j];
      z0 = fmaf(xr[      j], mj, z0);
      z1 = fmaf(xr[ 64 + j], mj, z1);
      z2 = fmaf(xr[128 + j], mj, z2);
      z3 = fmaf(xr[192 + j], mj, z3);
    }
    const float* mc = M + 4*kb;
#pragma unroll
    for (int i=0;i<64;i++){
      float c = col[i];
      c = fmaf(mc[i*64+0], z0, c);
      c = fmaf(mc[i*64+1], z1, c);
      c = fmaf(mc[i*64+2], z2, c);
      c = fmaf(mc[i*64+3], z3, c);
      col[i] = c;
    }
  }
}

// ================= K1: batch mean =================
__global__ __launch_bounds__(256) void k_mean(const float* __restrict__ X, float* __restrict__ meanAcc){
  const int tid=threadIdx.x; const int blk=blockIdx.x;
  float acc[16];
#pragma unroll
  for (int j=0;j<16;j++) acc[j]=0.f;
  const float* p = X + (size_t)blk*32*4096;
  for (int b2=0;b2<32;b2++){
#pragma unroll
    for (int j=0;j<16;j++) acc[j] += p[(size_t)b2*4096 + tid + 256*j];
  }
#pragma unroll
  for (int j=0;j<16;j++) atomicAdd(&meanAcc[tid+256*j], acc[j]*(1.0f/4096.0f));
}

// ================= 256-thread LDS matmul (col-major, stride LD2) =================
template<int MODE>
__device__ __forceinline__ void mmc256(float* __restrict__ dst, const float* __restrict__ A,
                                       const float* __restrict__ B, const float p0){
  const int tid=threadIdx.x; const int t=tid&63; const int i0=(tid>>6)*16;
  float acc[16];
#pragma unroll
  for (int j=0;j<16;j++) acc[j]=0.f;
#pragma unroll 4
  for (int k=0;k<64;k++){
    float bk = B[t*LD2+k];
#pragma unroll
    for (int j=0;j<16;j++) acc[j] = fmaf(A[k*LD2+i0+j], bk, acc[j]);
  }
  __syncthreads();
#pragma unroll
  for (int j=0;j<16;j++){
    int i=i0+j;
    float v=acc[j];
    if (MODE==1) v*=0.5f;
    if (MODE==2) v = ((i==t)?3.0f:0.0f) - v;
    if (MODE==3) v = v + ((i==t)?p0:0.0f);
    dst[t*LD2+i]=v;
  }
  __syncthreads();
}

__device__ __forceinline__ void chol_lds(float* __restrict__ C, const int tid, const int t, const int g){
  for (int j=0;j<64;j++){
    if (tid<64){
      float ljj = sqrtf(C[j*LD2+j]);
      float rinv = 1.0f/ljj;
      if (tid>=j) C[j*LD2+tid] = (tid==j)? ljj : C[j*LD2+tid]*rinv;
    }
    __syncthreads();
    for (int c=j+1+g; c<64; c+=4){
      float ljc = C[j*LD2+c];
      if (t>=c) C[c*LD2+t] -= C[j*LD2+t]*ljc;
    }
    __syncthreads();
  }
}

// ================= K2: Ms = mean^{1/2}, Mis = mean^{-1/2} via Newton-Schulz ====
__global__ __launch_bounds__(256) void k_sqrtmean(const float* __restrict__ meanw,
                                                  float* __restrict__ Msg, float* __restrict__ Misg){
  __shared__ float bufY[64*LD2], bufZ[64*LD2], bufT[64*LD2];
  const int tid=threadIdx.x;
  float tr=0.f;
  for (int k=0;k<64;k++) tr += meanw[k*65];
  const float alpha = 64.0f/tr;
  for (int e=tid; e<4096; e+=256){
    int r=e>>6, c=e&63;
    bufY[c*LD2+r] = alpha*meanw[e];
    bufZ[c*LD2+r] = (r==c)?1.0f:0.0f;
  }
  __syncthreads();
  float *pY=bufY, *pZ=bufZ, *pT=bufT;
  for (int it=0; it<5; ++it){
    mmc256<2>(pT, pZ, pY, 0.f);   // T = 3I - Z*Y
    mmc256<1>(pZ, pT, pZ, 0.f);   // Z' = 0.5*T*Z
    mmc256<1>(pT, pY, pT, 0.f);   // Y' = 0.5*Y*T
    float* tm=pY; pY=pT; pT=tm;
  }
  const float sa = sqrtf(alpha);
  const float isa = 1.0f/sa;
  for (int e=tid; e<4096; e+=256){
    int r=e>>6, c=e&63;
    Msg[e]  = pY[c*LD2+r]*isa;
    Misg[e] = pZ[c*LD2+r]*sa;
  }
}

// ================= K3: accumulate log(Mis X Mis) into slots =================
// Phase-1 = R10-PASSING config (1e-8, 7). The rescaled warm start
// (col * nrm^{-1/4}) requires phase-1 convergence (R9 failed at (1e-6,5));
// R11 confirmed the rescale is REQUIRED (W W^T = A^2 invariant).
template<bool STOREQ>
__global__ __launch_bounds__(64,2) void k_logaccum(const float* __restrict__ X,
                                                   const float* __restrict__ Mis,
                                                   float* __restrict__ slots,
                                                   float* __restrict__ Qs,
                                                   float* __restrict__ Ls){
  __shared__ __align__(16) float Wm[64*LDP];
  __shared__ float wcoef[64];
  const int t=threadIdx.x & 63; const int b=blockIdx.x;
  float col[64]; float nrm;
  cong_cols(X + (size_t)b*4096, Mis, col, t);
  jacobi64_lds(col, nrm, Wm, t, 7, 1e-8f);
  if (STOREQ){
#pragma unroll
    for (int j=0;j<16;j++)
      *reinterpret_cast<float4*>(Qs + (size_t)b*4096 + t*64 + 4*j) =
          make_float4(col[4*j],col[4*j+1],col[4*j+2],col[4*j+3]);
    Ls[(size_t)b*64+t] = nrm;
  }
  wcoef[t] = 0.5f*logf(nrm)/nrm;
  float acc[64];
#pragma unroll
  for (int i=0;i<64;i++) acc[i]=0.f;
#pragma unroll 1
  for (int k=0;k<64;k++){
    float f = wcoef[k]*Wm[k*LDP+t];
#pragma unroll
    for (int jj=0;jj<16;jj++){
      float4 a = *reinterpret_cast<const float4*>(&Wm[k*LDP+4*jj]);
      acc[4*jj+0]=fmaf(a.x,f,acc[4*jj+0]); acc[4*jj+1]=fmaf(a.y,f,acc[4*jj+1]);
      acc[4*jj+2]=fmaf(a.z,f,acc[4*jj+2]); acc[4*jj+3]=fmaf(a.w,f,acc[4*jj+3]);
    }
  }
  float* dst = slots + (size_t)(b & (NSLOTS-1))*4096;
#pragma unroll
  for (int i=0;i<64;i++) atomicAdd(&dst[i*64+t], acc[i]);
}

// ================= K4: exp(tang), batch_mean, chol, Linv, Lb, C=Linv*Ms ======
__global__ __launch_bounds__(256) void k_mid(const float* __restrict__ slots,
                                             const float* __restrict__ Msg,
                                             const float* __restrict__ bias,
                                             float* __restrict__ Linvg, float* __restrict__ Lbg,
                                             float* __restrict__ Cg){
  __shared__ float b1[64*LD2], b2[64*LD2], b3[64*LD2];
  const int tid=threadIdx.x; const int t=tid&63; const int g=tid>>6;
  for (int e=tid; e<4096; e+=256){
    float s=0.f;
    for (int sl=0; sl<NSLOTS; ++sl) s += slots[(size_t)sl*4096+e];
    b1[(e&63)*LD2+(e>>6)] = s * (1.0f/(4096.0f*16.0f));
  }
  __syncthreads();
  for (int e=tid; e<4096; e+=256){
    int r=e>>6, c=e&63;
    b2[c*LD2+r] = (1.0f/40320.0f)*b1[c*LD2+r] + ((r==c)?(1.0f/5040.0f):0.0f);
  }
  __syncthreads();
  float *pR=b2, *pT=b3;
  const float cj0=1.f/720.f, cj1=1.f/120.f, cj2=1.f/24.f, cj3=1.f/6.f, cj4=0.5f, cj5=1.f, cj6=1.f;
  mmc256<3>(pT,b1,pR,cj0); { float* tm=pR; pR=pT; pT=tm; }
  mmc256<3>(pT,b1,pR,cj1); { float* tm=pR; pR=pT; pT=tm; }
  mmc256<3>(pT,b1,pR,cj2); { float* tm=pR; pR=pT; pT=tm; }
  mmc256<3>(pT,b1,pR,cj3); { float* tm=pR; pR=pT; pT=tm; }
  mmc256<3>(pT,b1,pR,cj4); { float* tm=pR; pR=pT; pT=tm; }
  mmc256<3>(pT,b1,pR,cj5); { float* tm=pR; pR=pT; pT=tm; }
  mmc256<3>(pT,b1,pR,cj6); { float* tm=pR; pR=pT; pT=tm; }
  for (int q=0;q<4;q++){ mmc256<0>(pT, pR, pR, 0.f); float* tm=pR; pR=pT; pT=tm; }
  for (int e=tid; e<4096; e+=256) b1[(e&63)*LD2+(e>>6)] = Msg[e];
  __syncthreads();
  mmc256<0>(pT, b1, pR, 0.f);   // T = Ms*E
  mmc256<0>(pR, pT, b1, 0.f);   // bm = T*Ms
  chol_lds(pR, tid, t, g);      // pR holds L (lower, col-major)
  if (tid<64){
    const int c=tid;
    for (int k=0;k<64;k++) pT[c*LD2+k]=0.f;
    for (int i=0;i<64;i++){
      float s = (i==c)?1.0f:0.0f;
      for (int k=0;k<i;k++) s -= pR[k*LD2+i]*pT[c*LD2+k];
      pT[c*LD2+i] = s / pR[i*LD2+i];
    }
  }
  __syncthreads();
  if (tid<64){
    const int c=tid;
    for (int i=0;i<64;i++) Linvg[i*64+c] = pT[c*LD2+i];
  }
  // C = Linv * Ms  (pT holds Linv col-major, b1 holds Ms col-major)
  mmc256<0>(pR, pT, b1, 0.f);   // pR[t*LD2+i] = C[i][t]
  for (int e=tid; e<4096; e+=256) Cg[e] = pR[(e&63)*LD2+(e>>6)];  // row-major
  for (int e=tid; e<4096; e+=256) b1[(e&63)*LD2+(e>>6)] = bias[e];
  __syncthreads();
  chol_lds(b1, tid, t, g);
  if (tid<64){
    const int c=tid;
    for (int i=0;i<64;i++) Lbg[i*64+c] = (c<=i)? b1[c*LD2+i] : 0.0f;
  }
}

// ================= K5: Xc eig via warm start, var accumulation =================
// WARM: W0 col t = C * (nrm^{-1/4} w_t) = C * (lam^{1/2} q_t).
// W0 W0^T = C A C^T = Xc up to phase-1 residual (small at (1e-8,7)).
template<bool WARM>
__global__ __launch_bounds__(64,2) void k_center(const float* __restrict__ X,
                                                 const float* __restrict__ Linv,
                                                 const float* __restrict__ Cg,
                                                 float* __restrict__ varAcc,
                                                 float* __restrict__ Qs, float* __restrict__ Ls){
  __shared__ __align__(16) float Wm[64*LDP];
  const int t=threadIdx.x & 63; const int b=blockIdx.x;
  float col[64]; float nrm;
  if (WARM){
    const float s = rsqrtf(sqrtf(Ls[(size_t)b*64+t]));   // nrm^{-1/4}
    const float* q1 = Qs + (size_t)b*4096 + t*64;
#pragma unroll
    for (int i=0;i<64;i++) col[i]=0.f;
#pragma unroll 1
    for (int kb=0;kb<16;kb++){
      float4 v = *reinterpret_cast<const float4*>(q1 + 4*kb);
      float x0=v.x*s, x1=v.y*s, x2=v.z*s, x3=v.w*s;
      const float* cc = Cg + 4*kb;
#pragma unroll
      for (int i=0;i<64;i++){
        float c = col[i];
        c = fmaf(cc[i*64+0], x0, c);
        c = fmaf(cc[i*64+1], x1, c);
        c = fmaf(cc[i*64+2], x2, c);
        c = fmaf(cc[i*64+3], x3, c);
        col[i] = c;
      }
    }
    jacobi64_lds(col, nrm, Wm, t, 8, 1e-10f);
  } else {
    cong_cols(X + (size_t)b*4096, Linv, col, t);
    jacobi64_lds(col, nrm, Wm, t, 10, 1e-10f);
  }
  float ll = 0.5f*logf(nrm);
  float f2 = ll*ll;
#pragma unroll
  for (int off=1; off<64; off<<=1) f2 += __shfl_xor(f2, off, 64);
  if (t==0) atomicAdd(varAcc, f2);
  if (WARM){
#pragma unroll
    for (int j=0;j<16;j++)
      *reinterpret_cast<float4*>(Qs + (size_t)b*4096 + t*64 + 4*j) =
          make_float4(col[4*j],col[4*j+1],col[4*j+2],col[4*j+3]);
    Ls[(size_t)b*64+t] = nrm;
  }
}

// ================= K7: Xs = sum lam^f q q^T ; out = Lb Xs Lb^T =================
template<bool LOADW>
__global__ __launch_bounds__(64,2) void k_out(const float* __restrict__ X,
                                              const float* __restrict__ Linv,
                                              const float* __restrict__ Qs,
                                              const float* __restrict__ Ls,
                                              const float* __restrict__ Lb,
                                              const float* __restrict__ varAcc,
                                              const float* __restrict__ shift,
                                              float* __restrict__ out){
  __shared__ __align__(16) float Wm[64*LDP];
  __shared__ float wcoef[64];
  const int t=threadIdx.x & 63; const int b=blockIdx.x;
  float col[64]; float nrm;
  if (LOADW){
#pragma unroll
    for (int j=0;j<16;j++){
      float4 v = *reinterpret_cast<const float4*>(Qs + (size_t)b*4096 + t*64 + 4*j);
      col[4*j+0]=v.x; col[4*j+1]=v.y; col[4*j+2]=v.z; col[4*j+3]=v.w;
    }
    nrm = Ls[(size_t)b*64+t];
#pragma unroll
    for (int j=0;j<16;j++)
      *reinterpret_cast<float4*>(&Wm[t*LDP+4*j]) = make_float4(col[4*j],col[4*j+1],col[4*j+2],col[4*j+3]);
  } else {
    cong_cols(X + (size_t)b*4096, Linv, col, t);
    jacobi64_lds(col, nrm, Wm, t, 10, 1e-10f);
  }
  __syncthreads();
  const float var = varAcc[0] * (1.0f/4096.0f);
  const float factor = shift[0] * rsqrtf(var + 1e-5f);
  wcoef[t] = expf((factor-2.0f)*0.5f*logf(nrm));   // lam^{f-2}
  __syncthreads();
  float acc[64];
#pragma unroll
  for (int i=0;i<64;i++) acc[i]=0.f;
#pragma unroll 1
  for (int k=0;k<64;k++){
    float f = wcoef[k]*Wm[k*LDP+t];
#pragma unroll
    for (int jj=0;jj<16;jj++){
      float4 a = *reinterpret_cast<const float4*>(&Wm[k*LDP+4*jj]);
      acc[4*jj+0]=fmaf(a.x,f,acc[4*jj+0]); acc[4*jj+1]=fmaf(a.y,f,acc[4*jj+1]);
      acc[4*jj+2]=fmaf(a.z,f,acc[4*jj+2]); acc[4*jj+3]=fmaf(a.w,f,acc[4*jj+3]);
    }
  }
  // T2 = Lb * Xs (single-wave block: all Wm reads above complete first)
#pragma unroll 2
  for (int i=0;i<64;i++){
    float s0=0.f,s1=0.f;
#pragma unroll
    for (int k=0;k<64;k+=2){ s0=fmaf(Lb[i*64+k],acc[k],s0); s1=fmaf(Lb[i*64+k+1],acc[k+1],s1); }
    Wm[t*LDP+i]=s0+s1;
  }
  float o[64];
#pragma unroll
  for (int i=0;i<64;i++) o[i]=0.f;
#pragma unroll 1
  for (int k=0;k<64;k++){
    float bk = Lb[t*64+k];
#pragma unroll
    for (int jj=0;jj<16;jj++){
      float4 a = *reinterpret_cast<const float4*>(&Wm[k*LDP+4*jj]);
      o[4*jj+0]=fmaf(a.x,bk,o[4*jj+0]); o[4*jj+1]=fmaf(a.y,bk,o[4*jj+1]);
      o[4*jj+2]=fmaf(a.z,bk,o[4*jj+2]); o[4*jj+3]=fmaf(a.w,bk,o[4*jj+3]);
    }
  }
  float* ob = out + (size_t)b*4096;
#pragma unroll
  for (int i=0;i<64;i++) ob[i*64+t] = o[i];
}

// =====================================================================
extern "C" void kernel_launch(void* const* d_in, const int* in_sizes, int n_in,
                              void* d_out, int out_size, void* d_ws, size_t ws_size,
                              hipStream_t stream){
  (void)in_sizes; (void)n_in; (void)out_size;
  const float* X     = (const float*)d_in[0];
  const float* bias  = (const float*)d_in[1];
  const float* shift = (const float*)d_in[2];
  float* out = (float*)d_out;
  float* ws  = (float*)d_ws;

  hipMemsetAsync(d_ws, 0, (size_t)WS_ZERO_FLOATS*sizeof(float), stream);
  k_mean<<<128,256,0,stream>>>(X, ws+OFF_MEAN);
  k_sqrtmean<<<1,256,0,stream>>>(ws+OFF_MEAN, ws+OFF_MS, ws+OFF_MIS);

  const bool big = ws_size >= (size_t)WS_FULL*sizeof(float);
  if (big){
    k_logaccum<true><<<NB,64,0,stream>>>(X, ws+OFF_MIS, ws+OFF_SLOTS, ws+OFF_Q, ws+OFF_LAM);
    k_mid<<<1,256,0,stream>>>(ws+OFF_SLOTS, ws+OFF_MS, bias, ws+OFF_LINV, ws+OFF_LB, ws+OFF_C);
    k_center<true><<<NB,64,0,stream>>>(X, ws+OFF_LINV, ws+OFF_C, ws+OFF_VAR, ws+OFF_Q, ws+OFF_LAM);
    k_out<true><<<NB,64,0,stream>>>(X, ws+OFF_LINV, ws+OFF_Q, ws+OFF_LAM, ws+OFF_LB, ws+OFF_VAR, shift, out);
  } else {
    k_logaccum<false><<<NB,64,0,stream>>>(X, ws+OFF_MIS, ws+OFF_SLOTS, nullptr, nullptr);
    k_mid<<<1,256,0,stream>>>(ws+OFF_SLOTS, ws+OFF_MS, bias, ws+OFF_LINV, ws+OFF_LB, ws+OFF_C);
    k_center<false><<<NB,64,0,stream>>>(X, ws+OFF_LINV, nullptr, ws+OFF_VAR, nullptr, nullptr);
    k_out<false><<<NB,64,0,stream>>>(X, ws+OFF_LINV, nullptr, nullptr, ws+OFF_LB, ws+OFF_VAR, shift, out);
  }
}

// Round 14
// 2897.382 us; speedup vs baseline: 1.1230x; 1.0135x over previous
//
#include <hip/hip_runtime.h>
#include <cstdint>
#include <cstddef>

#define NB 4096
#define NN 64
#define LDP 68   // LDS stride: 272B = 16B-aligned, spreads lanes over bank-quads
#define LD2 65   // single-block kernels: LDS stride (scalar access, conflict-free)

// ---- workspace float offsets ----
#define OFF_MEAN  0
#define OFF_MS    4096
#define OFF_MIS   8192
#define OFF_LINV  12288
#define OFF_LB    16384
#define OFF_VAR   20480
#define OFF_SLOTS 24576
#define NSLOTS    32
#define OFF_C     (OFF_SLOTS + NSLOTS*4096)        // 155648 (C = Linv*Ms)
#define WS_ZERO_FLOATS (OFF_SLOTS + NSLOTS*4096)   // zero slots+var region
#define OFF_Q     286720                            // keep legacy layout
#define OFF_LAM   (OFF_Q + (size_t)NB*4096)
#define WS_FULL   (OFF_LAM + (size_t)NB*64)

typedef float f32x4 __attribute__((ext_vector_type(4)));

__device__ __forceinline__ float bperm(int pad, float v){
  return __int_as_float(__builtin_amdgcn_ds_bpermute(pad, __float_as_int(v)));
}

// Generic LDS pointer -> 32-bit LDS byte address.
__device__ __forceinline__ unsigned lds_addr(const void* p){
  return (unsigned)(unsigned long long)(uintptr_t)p;
}

// =====================================================================
// One-sided Jacobi with LDS master copy (col-major, stride LDP).
// Partner column fetched with 16 inline-asm ds_read_b128 (R13: asm regs
// can't be rematerialized; independent asm statements pipeline; one
// manual lgkmcnt(0) threaded through the q regs + sched_barrier).
// Occupancy is LDS-capped at 9 waves/CU (17.9KB/block) -> the round
// chain is latency-bound; round-count reduction is the remaining lever.
// =====================================================================
__device__ __forceinline__ void jacobi64_lds(float col[64], float& nrm,
                                             float* __restrict__ Wm,
                                             const int t,
                                             const int maxsweep, const float tolsq) {
  {
#pragma unroll
    for (int jb=0;jb<16;jb++)
      *reinterpret_cast<f32x4*>(Wm + t*LDP + 4*jb) =
        (f32x4){col[4*jb],col[4*jb+1],col[4*jb+2],col[4*jb+3]};
    float n0=0.f,n1=0.f,n2=0.f,n3=0.f;
#pragma unroll
    for (int j=0;j<64;j+=4){
      n0=fmaf(col[j+0],col[j+0],n0); n1=fmaf(col[j+1],col[j+1],n1);
      n2=fmaf(col[j+2],col[j+2],n2); n3=fmaf(col[j+3],col[j+3],n3);
    }
    nrm=(n0+n1)+(n2+n3);
  }
#pragma unroll 1
  for (int sw=0; sw<maxsweep; ++sw){
    int anyrot=0;
#pragma unroll 1
    for (int m=1; m<64; ++m){
      const int pad = ((t ^ m) << 2);
      const unsigned pbase = lds_addr(Wm + (t ^ m)*LDP);
      float pn = bperm(pad, nrm);
      f32x4 q0,q1,q2,q3,q4,q5,q6,q7,q8,q9,q10,q11,q12,q13,q14,q15;
      asm volatile("ds_read_b128 %0, %1"             : "=v"(q0)  : "v"(pbase) : "memory");
      asm volatile("ds_read_b128 %0, %1 offset:16"   : "=v"(q1)  : "v"(pbase));
      asm volatile("ds_read_b128 %0, %1 offset:32"   : "=v"(q2)  : "v"(pbase));
      asm volatile("ds_read_b128 %0, %1 offset:48"   : "=v"(q3)  : "v"(pbase));
      asm volatile("ds_read_b128 %0, %1 offset:64"   : "=v"(q4)  : "v"(pbase));
      asm volatile("ds_read_b128 %0, %1 offset:80"   : "=v"(q5)  : "v"(pbase));
      asm volatile("ds_read_b128 %0, %1 offset:96"   : "=v"(q6)  : "v"(pbase));
      asm volatile("ds_read_b128 %0, %1 offset:112"  : "=v"(q7)  : "v"(pbase));
      asm volatile("ds_read_b128 %0, %1 offset:128"  : "=v"(q8)  : "v"(pbase));
      asm volatile("ds_read_b128 %0, %1 offset:144"  : "=v"(q9)  : "v"(pbase));
      asm volatile("ds_read_b128 %0, %1 offset:160"  : "=v"(q10) : "v"(pbase));
      asm volatile("ds_read_b128 %0, %1 offset:176"  : "=v"(q11) : "v"(pbase));
      asm volatile("ds_read_b128 %0, %1 offset:192"  : "=v"(q12) : "v"(pbase));
      asm volatile("ds_read_b128 %0, %1 offset:208"  : "=v"(q13) : "v"(pbase));
      asm volatile("ds_read_b128 %0, %1 offset:224"  : "=v"(q14) : "v"(pbase));
      asm volatile("ds_read_b128 %0, %1 offset:240"  : "=v"(q15) : "v"(pbase));
      asm volatile("s_waitcnt lgkmcnt(0)"
        : "+v"(q0),"+v"(q1),"+v"(q2),"+v"(q3),"+v"(q4),"+v"(q5),"+v"(q6),"+v"(q7));
      asm volatile(""
        : "+v"(q8),"+v"(q9),"+v"(q10),"+v"(q11),"+v"(q12),"+v"(q13),"+v"(q14),"+v"(q15));
      __builtin_amdgcn_sched_barrier(0);
      float a0=0.f,a1=0.f,a2=0.f,a3=0.f;
#define DOT4(JB,Q) \
      a0=fmaf(col[4*JB+0],Q[0],a0); a1=fmaf(col[4*JB+1],Q[1],a1); \
      a2=fmaf(col[4*JB+2],Q[2],a2); a3=fmaf(col[4*JB+3],Q[3],a3);
      DOT4(0,q0) DOT4(1,q1) DOT4(2,q2) DOT4(3,q3)
      DOT4(4,q4) DOT4(5,q5) DOT4(6,q6) DOT4(7,q7)
      DOT4(8,q8) DOT4(9,q9) DOT4(10,q10) DOT4(11,q11)
      DOT4(12,q12) DOT4(13,q13) DOT4(14,q14) DOT4(15,q15)
#undef DOT4
      float apq=(a0+a1)+(a2+a3);
      const bool isP = t < (t ^ m);
      float app = isP ? nrm : pn;
      float aqq = isP ? pn : nrm;
      const bool rot = (apq*apq > tolsq*app*aqq);
      if (__any((int)rot)){
        float tau = (aqq - app) / (2.0f*apq);
        float tt  = 1.0f / (fabsf(tau) + sqrtf(fmaf(tau,tau,1.0f)));
        tt = (tau < 0.0f) ? -tt : tt;
        float cc = rsqrtf(fmaf(tt,tt,1.0f));
        float ss = cc*tt;
        float ccv = rot ? cc : 1.0f;
        float sgv = rot ? (isP ? -ss : ss) : 0.0f;
#define ROT4(JB,Q) \
        col[4*JB+0]=fmaf(ccv,col[4*JB+0],sgv*Q[0]); \
        col[4*JB+1]=fmaf(ccv,col[4*JB+1],sgv*Q[1]); \
        col[4*JB+2]=fmaf(ccv,col[4*JB+2],sgv*Q[2]); \
        col[4*JB+3]=fmaf(ccv,col[4*JB+3],sgv*Q[3]);
        ROT4(0,q0) ROT4(1,q1) ROT4(2,q2) ROT4(3,q3)
        ROT4(4,q4) ROT4(5,q5) ROT4(6,q6) ROT4(7,q7)
        ROT4(8,q8) ROT4(9,q9) ROT4(10,q10) ROT4(11,q11)
        ROT4(12,q12) ROT4(13,q13) ROT4(14,q14) ROT4(15,q15)
#undef ROT4
        float tq = tt*apq;
        nrm += rot ? (isP ? -tq : tq) : 0.0f;
        if (rot){
#pragma unroll
          for (int jb=0;jb<16;jb++)
            *reinterpret_cast<f32x4*>(Wm + t*LDP + 4*jb) =
              (f32x4){col[4*jb],col[4*jb+1],col[4*jb+2],col[4*jb+3]};
        }
        anyrot = 1;
      }
    }
    if (!__any(anyrot)) break;
  }
  {
    float n0=0.f,n1=0.f,n2=0.f,n3=0.f;
#pragma unroll
    for (int j=0;j<64;j+=4){
      n0=fmaf(col[j+0],col[j+0],n0); n1=fmaf(col[j+1],col[j+1],n1);
      n2=fmaf(col[j+2],col[j+2],n2); n3=fmaf(col[j+3],col[j+3],n3);
    }
    nrm=(n0+n1)+(n2+n3);
  }
}

// =====================================================================
// LDS-free congruence: col = (M * Xb * M^T) column t = M * (Xb * m_t).
// =====================================================================
__device__ __forceinline__ void cong_cols(const float* __restrict__ Xb,
                                          const float* __restrict__ M,
                                          float col[64], const int t){
  float mrow[64];
#pragma unroll
  for (int j=0;j<16;j++){
    float4 v = *reinterpret_cast<const float4*>(M + t*64 + 4*j);
    mrow[4*j+0]=v.x; mrow[4*j+1]=v.y; mrow[4*j+2]=v.z; mrow[4*j+3]=v.w;
  }
#pragma unroll
  for (int i=0;i<64;i++) col[i]=0.f;
#pragma unroll 1
  for (int kb=0;kb<16;kb++){
    const float* xr = Xb + kb*256;
    float z0=0.f,z1=0.f,z2=0.f,z3=0.f;
#pragma unroll
    for (int j=0;j<64;j++){
      float mj = mrow[j];
      z0 = fmaf(xr[      j], mj, z0);
      z1 = fmaf(xr[ 64 + j], mj, z1);
      z2 = fmaf(xr[128 + j], mj, z2);
      z3 = fmaf(xr[192 + j], mj, z3);
    }
    const float* mc = M + 4*kb;
#pragma unroll
    for (int i=0;i<64;i++){
      float c = col[i];
      c = fmaf(mc[i*64+0], z0, c);
      c = fmaf(mc[i*64+1], z1, c);
      c = fmaf(mc[i*64+2], z2, c);
      c = fmaf(mc[i*64+3], z3, c);
      col[i] = c;
    }
  }
}

// ================= K1: batch mean =================
__global__ __launch_bounds__(256) void k_mean(const float* __restrict__ X, float* __restrict__ meanAcc){
  const int tid=threadIdx.x; const int blk=blockIdx.x;
  float acc[16];
#pragma unroll
  for (int j=0;j<16;j++) acc[j]=0.f;
  const float* p = X + (size_t)blk*32*4096;
  for (int b2=0;b2<32;b2++){
#pragma unroll
    for (int j=0;j<16;j++) acc[j] += p[(size_t)b2*4096 + tid + 256*j];
  }
#pragma unroll
  for (int j=0;j<16;j++) atomicAdd(&meanAcc[tid+256*j], acc[j]*(1.0f/4096.0f));
}

// ================= 256-thread LDS matmul (col-major, stride LD2) =================
template<int MODE>
__device__ __forceinline__ void mmc256(float* __restrict__ dst, const float* __restrict__ A,
                                       const float* __restrict__ B, const float p0){
  const int tid=threadIdx.x; const int t=tid&63; const int i0=(tid>>6)*16;
  float acc[16];
#pragma unroll
  for (int j=0;j<16;j++) acc[j]=0.f;
#pragma unroll 4
  for (int k=0;k<64;k++){
    float bk = B[t*LD2+k];
#pragma unroll
    for (int j=0;j<16;j++) acc[j] = fmaf(A[k*LD2+i0+j], bk, acc[j]);
  }
  __syncthreads();
#pragma unroll
  for (int j=0;j<16;j++){
    int i=i0+j;
    float v=acc[j];
    if (MODE==1) v*=0.5f;
    if (MODE==2) v = ((i==t)?3.0f:0.0f) - v;
    if (MODE==3) v = v + ((i==t)?p0:0.0f);
    dst[t*LD2+i]=v;
  }
  __syncthreads();
}

__device__ __forceinline__ void chol_lds(float* __restrict__ C, const int tid, const int t, const int g){
  for (int j=0;j<64;j++){
    if (tid<64){
      float ljj = sqrtf(C[j*LD2+j]);
      float rinv = 1.0f/ljj;
      if (tid>=j) C[j*LD2+tid] = (tid==j)? ljj : C[j*LD2+tid]*rinv;
    }
    __syncthreads();
    for (int c=j+1+g; c<64; c+=4){
      float ljc = C[j*LD2+c];
      if (t>=c) C[c*LD2+t] -= C[j*LD2+t]*ljc;
    }
    __syncthreads();
  }
}

// ================= K2: Ms = mean^{1/2}, Mis = mean^{-1/2} via Newton-Schulz ====
__global__ __launch_bounds__(256) void k_sqrtmean(const float* __restrict__ meanw,
                                                  float* __restrict__ Msg, float* __restrict__ Misg){
  __shared__ float bufY[64*LD2], bufZ[64*LD2], bufT[64*LD2];
  const int tid=threadIdx.x;
  float tr=0.f;
  for (int k=0;k<64;k++) tr += meanw[k*65];
  const float alpha = 64.0f/tr;
  for (int e=tid; e<4096; e+=256){
    int r=e>>6, c=e&63;
    bufY[c*LD2+r] = alpha*meanw[e];
    bufZ[c*LD2+r] = (r==c)?1.0f:0.0f;
  }
  __syncthreads();
  float *pY=bufY, *pZ=bufZ, *pT=bufT;
  for (int it=0; it<5; ++it){
    mmc256<2>(pT, pZ, pY, 0.f);   // T = 3I - Z*Y
    mmc256<1>(pZ, pT, pZ, 0.f);   // Z' = 0.5*T*Z
    mmc256<1>(pT, pY, pT, 0.f);   // Y' = 0.5*Y*T
    float* tm=pY; pY=pT; pT=tm;
  }
  const float sa = sqrtf(alpha);
  const float isa = 1.0f/sa;
  for (int e=tid; e<4096; e+=256){
    int r=e>>6, c=e&63;
    Msg[e]  = pY[c*LD2+r]*isa;
    Misg[e] = pZ[c*LD2+r]*sa;
  }
}

// ================= K3: accumulate log(Mis X Mis) into slots =================
// Phase-1 (1e-7, 6): one sweep fewer than R13's passing (1e-8, 7), one
// sweep MORE + sqrt(10) tighter than R9's failing (1e-6, 5) -- R9's error
// was dominated by the maxsweep-5 cap (quadratic convergence: the 6th
// sweep squares the residual). Warm-start rescale requires this residual
// to stay small; predicted phase-1 residual ~3e-4 -> total ~1e-2 < 2.2e-2.
template<bool STOREQ>
__global__ __launch_bounds__(64,2) void k_logaccum(const float* __restrict__ X,
                                                   const float* __restrict__ Mis,
                                                   float* __restrict__ slots,
                                                   float* __restrict__ Qs,
                                                   float* __restrict__ Ls){
  __shared__ __align__(16) float Wm[64*LDP];
  __shared__ float wcoef[64];
  const int t=threadIdx.x & 63; const int b=blockIdx.x;
  float col[64]; float nrm;
  cong_cols(X + (size_t)b*4096, Mis, col, t);
  jacobi64_lds(col, nrm, Wm, t, 6, 1e-7f);
  if (STOREQ){
#pragma unroll
    for (int j=0;j<16;j++)
      *reinterpret_cast<float4*>(Qs + (size_t)b*4096 + t*64 + 4*j) =
          make_float4(col[4*j],col[4*j+1],col[4*j+2],col[4*j+3]);
    Ls[(size_t)b*64+t] = nrm;
  }
  wcoef[t] = 0.5f*logf(nrm)/nrm;
  float acc[64];
#pragma unroll
  for (int i=0;i<64;i++) acc[i]=0.f;
#pragma unroll 1
  for (int k=0;k<64;k++){
    float f = wcoef[k]*Wm[k*LDP+t];
#pragma unroll
    for (int jj=0;jj<16;jj++){
      float4 a = *reinterpret_cast<const float4*>(&Wm[k*LDP+4*jj]);
      acc[4*jj+0]=fmaf(a.x,f,acc[4*jj+0]); acc[4*jj+1]=fmaf(a.y,f,acc[4*jj+1]);
      acc[4*jj+2]=fmaf(a.z,f,acc[4*jj+2]); acc[4*jj+3]=fmaf(a.w,f,acc[4*jj+3]);
    }
  }
  float* dst = slots + (size_t)(b & (NSLOTS-1))*4096;
#pragma unroll
  for (int i=0;i<64;i++) atomicAdd(&dst[i*64+t], acc[i]);
}

// ================= K4: exp(tang), batch_mean, chol, Linv, Lb, C=Linv*Ms ======
__global__ __launch_bounds__(256) void k_mid(const float* __restrict__ slots,
                                             const float* __restrict__ Msg,
                                             const float* __restrict__ bias,
                                             float* __restrict__ Linvg, float* __restrict__ Lbg,
                                             float* __restrict__ Cg){
  __shared__ float b1[64*LD2], b2[64*LD2], b3[64*LD2];
  const int tid=threadIdx.x; const int t=tid&63; const int g=tid>>6;
  for (int e=tid; e<4096; e+=256){
    float s=0.f;
    for (int sl=0; sl<NSLOTS; ++sl) s += slots[(size_t)sl*4096+e];
    b1[(e&63)*LD2+(e>>6)] = s * (1.0f/(4096.0f*16.0f));
  }
  __syncthreads();
  for (int e=tid; e<4096; e+=256){
    int r=e>>6, c=e&63;
    b2[c*LD2+r] = (1.0f/40320.0f)*b1[c*LD2+r] + ((r==c)?(1.0f/5040.0f):0.0f);
  }
  __syncthreads();
  float *pR=b2, *pT=b3;
  const float cj0=1.f/720.f, cj1=1.f/120.f, cj2=1.f/24.f, cj3=1.f/6.f, cj4=0.5f, cj5=1.f, cj6=1.f;
  mmc256<3>(pT,b1,pR,cj0); { float* tm=pR; pR=pT; pT=tm; }
  mmc256<3>(pT,b1,pR,cj1); { float* tm=pR; pR=pT; pT=tm; }
  mmc256<3>(pT,b1,pR,cj2); { float* tm=pR; pR=pT; pT=tm; }
  mmc256<3>(pT,b1,pR,cj3); { float* tm=pR; pR=pT; pT=tm; }
  mmc256<3>(pT,b1,pR,cj4); { float* tm=pR; pR=pT; pT=tm; }
  mmc256<3>(pT,b1,pR,cj5); { float* tm=pR; pR=pT; pT=tm; }
  mmc256<3>(pT,b1,pR,cj6); { float* tm=pR; pR=pT; pT=tm; }
  for (int q=0;q<4;q++){ mmc256<0>(pT, pR, pR, 0.f); float* tm=pR; pR=pT; pT=tm; }
  for (int e=tid; e<4096; e+=256) b1[(e&63)*LD2+(e>>6)] = Msg[e];
  __syncthreads();
  mmc256<0>(pT, b1, pR, 0.f);   // T = Ms*E
  mmc256<0>(pR, pT, b1, 0.f);   // bm = T*Ms
  chol_lds(pR, tid, t, g);      // pR holds L (lower, col-major)
  if (tid<64){
    const int c=tid;
    for (int k=0;k<64;k++) pT[c*LD2+k]=0.f;
    for (int i=0;i<64;i++){
      float s = (i==c)?1.0f:0.0f;
      for (int k=0;k<i;k++) s -= pR[k*LD2+i]*pT[c*LD2+k];
      pT[c*LD2+i] = s / pR[i*LD2+i];
    }
  }
  __syncthreads();
  if (tid<64){
    const int c=tid;
    for (int i=0;i<64;i++) Linvg[i*64+c] = pT[c*LD2+i];
  }
  // C = Linv * Ms  (pT holds Linv col-major, b1 holds Ms col-major)
  mmc256<0>(pR, pT, b1, 0.f);   // pR[t*LD2+i] = C[i][t]
  for (int e=tid; e<4096; e+=256) Cg[e] = pR[(e&63)*LD2+(e>>6)];  // row-major
  for (int e=tid; e<4096; e+=256) b1[(e&63)*LD2+(e>>6)] = bias[e];
  __syncthreads();
  chol_lds(b1, tid, t, g);
  if (tid<64){
    const int c=tid;
    for (int i=0;i<64;i++) Lbg[i*64+c] = (c<=i)? b1[c*LD2+i] : 0.0f;
  }
}

// ================= K5: Xc eig via warm start, var accumulation =================
// WARM: W0 col t = C * (nrm^{-1/4} w_t) = C * (lam^{1/2} q_t).
// W0 W0^T = C A C^T = Xc up to phase-1 residual.
template<bool WARM>
__global__ __launch_bounds__(64,2) void k_center(const float* __restrict__ X,
                                                 const float* __restrict__ Linv,
                                                 const float* __restrict__ Cg,
                                                 float* __restrict__ varAcc,
                                                 float* __restrict__ Qs, float* __restrict__ Ls){
  __shared__ __align__(16) float Wm[64*LDP];
  const int t=threadIdx.x & 63; const int b=blockIdx.x;
  float col[64]; float nrm;
  if (WARM){
    const float s = rsqrtf(sqrtf(Ls[(size_t)b*64+t]));   // nrm^{-1/4}
    const float* q1 = Qs + (size_t)b*4096 + t*64;
#pragma unroll
    for (int i=0;i<64;i++) col[i]=0.f;
#pragma unroll 1
    for (int kb=0;kb<16;kb++){
      float4 v = *reinterpret_cast<const float4*>(q1 + 4*kb);
      float x0=v.x*s, x1=v.y*s, x2=v.z*s, x3=v.w*s;
      const float* cc = Cg + 4*kb;
#pragma unroll
      for (int i=0;i<64;i++){
        float c = col[i];
        c = fmaf(cc[i*64+0], x0, c);
        c = fmaf(cc[i*64+1], x1, c);
        c = fmaf(cc[i*64+2], x2, c);
        c = fmaf(cc[i*64+3], x3, c);
        col[i] = c;
      }
    }
    jacobi64_lds(col, nrm, Wm, t, 8, 1e-10f);
  } else {
    cong_cols(X + (size_t)b*4096, Linv, col, t);
    jacobi64_lds(col, nrm, Wm, t, 10, 1e-10f);
  }
  float ll = 0.5f*logf(nrm);
  float f2 = ll*ll;
#pragma unroll
  for (int off=1; off<64; off<<=1) f2 += __shfl_xor(f2, off, 64);
  if (t==0) atomicAdd(varAcc, f2);
  if (WARM){
#pragma unroll
    for (int j=0;j<16;j++)
      *reinterpret_cast<float4*>(Qs + (size_t)b*4096 + t*64 + 4*j) =
          make_float4(col[4*j],col[4*j+1],col[4*j+2],col[4*j+3]);
    Ls[(size_t)b*64+t] = nrm;
  }
}

// ================= K7: Xs = sum lam^f q q^T ; out = Lb Xs Lb^T =================
template<bool LOADW>
__global__ __launch_bounds__(64,2) void k_out(const float* __restrict__ X,
                                              const float* __restrict__ Linv,
                                              const float* __restrict__ Qs,
                                              const float* __restrict__ Ls,
                                              const float* __restrict__ Lb,
                                              const float* __restrict__ varAcc,
                                              const float* __restrict__ shift,
                                              float* __restrict__ out){
  __shared__ __align__(16) float Wm[64*LDP];
  __shared__ float wcoef[64];
  const int t=threadIdx.x & 63; const int b=blockIdx.x;
  float col[64]; float nrm;
  if (LOADW){
#pragma unroll
    for (int j=0;j<16;j++){
      float4 v = *reinterpret_cast<const float4*>(Qs + (size_t)b*4096 + t*64 + 4*j);
      col[4*j+0]=v.x; col[4*j+1]=v.y; col[4*j+2]=v.z; col[4*j+3]=v.w;
    }
    nrm = Ls[(size_t)b*64+t];
#pragma unroll
    for (int j=0;j<16;j++)
      *reinterpret_cast<float4*>(&Wm[t*LDP+4*j]) = make_float4(col[4*j],col[4*j+1],col[4*j+2],col[4*j+3]);
  } else {
    cong_cols(X + (size_t)b*4096, Linv, col, t);
    jacobi64_lds(col, nrm, Wm, t, 10, 1e-10f);
  }
  __syncthreads();
  const float var = varAcc[0] * (1.0f/4096.0f);
  const float factor = shift[0] * rsqrtf(var + 1e-5f);
  wcoef[t] = expf((factor-2.0f)*0.5f*logf(nrm));   // lam^{f-2}
  __syncthreads();
  float acc[64];
#pragma unroll
  for (int i=0;i<64;i++) acc[i]=0.f;
#pragma unroll 1
  for (int k=0;k<64;k++){
    float f = wcoef[k]*Wm[k*LDP+t];
#pragma unroll
    for (int jj=0;jj<16;jj++){
      float4 a = *reinterpret_cast<const float4*>(&Wm[k*LDP+4*jj]);
      acc[4*jj+0]=fmaf(a.x,f,acc[4*jj+0]); acc[4*jj+1]=fmaf(a.y,f,acc[4*jj+1]);
      acc[4*jj+2]=fmaf(a.z,f,acc[4*jj+2]); acc[4*jj+3]=fmaf(a.w,f,acc[4*jj+3]);
    }
  }
  // T2 = Lb * Xs (single-wave block: all Wm reads above complete first)
#pragma unroll 2
  for (int i=0;i<64;i++){
    float s0=0.f,s1=0.f;
#pragma unroll
    for (int k=0;k<64;k+=2){ s0=fmaf(Lb[i*64+k],acc[k],s0); s1=fmaf(Lb[i*64+k+1],acc[k+1],s1); }
    Wm[t*LDP+i]=s0+s1;
  }
  float o[64];
#pragma unroll
  for (int i=0;i<64;i++) o[i]=0.f;
#pragma unroll 1
  for (int k=0;k<64;k++){
    float bk = Lb[t*64+k];
#pragma unroll
    for (int jj=0;jj<16;jj++){
      float4 a = *reinterpret_cast<const float4*>(&Wm[k*LDP+4*jj]);
      o[4*jj+0]=fmaf(a.x,bk,o[4*jj+0]); o[4*jj+1]=fmaf(a.y,bk,o[4*jj+1]);
      o[4*jj+2]=fmaf(a.z,bk,o[4*jj+2]); o[4*jj+3]=fmaf(a.w,bk,o[4*jj+3]);
    }
  }
  float* ob = out + (size_t)b*4096;
#pragma unroll
  for (int i=0;i<64;i++) ob[i*64+t] = o[i];
}

// =====================================================================
extern "C" void kernel_launch(void* const* d_in, const int* in_sizes, int n_in,
                              void* d_out, int out_size, void* d_ws, size_t ws_size,
                              hipStream_t stream){
  (void)in_sizes; (void)n_in; (void)out_size;
  const float* X     = (const float*)d_in[0];
  const float* bias  = (const float*)d_in[1];
  const float* shift = (const float*)d_in[2];
  float* out = (float*)d_out;
  float* ws  = (float*)d_ws;

  hipMemsetAsync(d_ws, 0, (size_t)WS_ZERO_FLOATS*sizeof(float), stream);
  k_mean<<<128,256,0,stream>>>(X, ws+OFF_MEAN);
  k_sqrtmean<<<1,256,0,stream>>>(ws+OFF_MEAN, ws+OFF_MS, ws+OFF_MIS);

  const bool big = ws_size >= (size_t)WS_FULL*sizeof(float);
  if (big){
    k_logaccum<true><<<NB,64,0,stream>>>(X, ws+OFF_MIS, ws+OFF_SLOTS, ws+OFF_Q, ws+OFF_LAM);
    k_mid<<<1,256,0,stream>>>(ws+OFF_SLOTS, ws+OFF_MS, bias, ws+OFF_LINV, ws+OFF_LB, ws+OFF_C);
    k_center<true><<<NB,64,0,stream>>>(X, ws+OFF_LINV, ws+OFF_C, ws+OFF_VAR, ws+OFF_Q, ws+OFF_LAM);
    k_out<true><<<NB,64,0,stream>>>(X, ws+OFF_LINV, ws+OFF_Q, ws+OFF_LAM, ws+OFF_LB, ws+OFF_VAR, shift, out);
  } else {
    k_logaccum<false><<<NB,64,0,stream>>>(X, ws+OFF_MIS, ws+OFF_SLOTS, nullptr, nullptr);
    k_mid<<<1,256,0,stream>>>(ws+OFF_SLOTS, ws+OFF_MS, bias, ws+OFF_LINV, ws+OFF_LB, ws+OFF_C);
    k_center<false><<<NB,64,0,stream>>>(X, ws+OFF_LINV, nullptr, ws+OFF_VAR, nullptr, nullptr);
    k_out<false><<<NB,64,0,stream>>>(X, ws+OFF_LINV, nullptr, nullptr, ws+OFF_LB, ws+OFF_VAR, shift, out);
  }
}

// Round 16
// 2451.994 us; speedup vs baseline: 1.3270x; 1.1816x over previous
//
#include <hip/hip_runtime.h>
#include <cstdint>
#include <cstddef>

#define NB 4096
#define NN 64
#define LDP 68   // LDS stride: 272B = 16B-aligned, spreads lanes over bank-quads
#define LD2 65   // single-block kernels: LDS stride (scalar access, conflict-free)

// ---- workspace float offsets ----
#define OFF_MEAN  0
#define OFF_MS    4096
#define OFF_MIS   8192
#define OFF_LINV  12288
#define OFF_LB    16384
#define OFF_VAR   20480
#define OFF_SLOTS 24576
#define NSLOTS    32
#define OFF_C     (OFF_SLOTS + NSLOTS*4096)        // 155648 (C = Linv*Ms)
#define WS_ZERO_FLOATS (OFF_SLOTS + NSLOTS*4096)   // zero slots+var region
#define OFF_Q     286720                            // keep legacy layout
#define OFF_LAM   (OFF_Q + (size_t)NB*4096)
#define WS_FULL   (OFF_LAM + (size_t)NB*64)

typedef float f32x4 __attribute__((ext_vector_type(4)));
typedef float f32x2 __attribute__((ext_vector_type(2)));

__device__ __forceinline__ f32x2 pkf(f32x2 a, f32x2 b, f32x2 c){
  return __builtin_elementwise_fma(a,b,c);
}
__device__ __forceinline__ f32x2 mk2(float a, float b){ f32x2 r; r[0]=a; r[1]=b; return r; }

__device__ __forceinline__ float bperm(int pad, float v){
  return __int_as_float(__builtin_amdgcn_ds_bpermute(pad, __float_as_int(v)));
}

// Generic LDS pointer -> 32-bit LDS byte address.
__device__ __forceinline__ unsigned lds_addr(const void* p){
  return (unsigned)(unsigned long long)(uintptr_t)p;
}

// =====================================================================
// One-sided Jacobi with LDS master copy (col-major, stride LDP).
// Partner column fetched with 16 inline-asm ds_read_b128 (R13: asm regs
// can't be rematerialized; independent asm statements pipeline; one
// manual lgkmcnt(0) threaded through the q regs + sched_barrier).
// R16: column state + dot + rotate in f32x2 packed math (V_PK_FMA_F32,
// 2 FP32 FMA/instr on gfx950) -> ~halves the VALU stream per round.
// =====================================================================
__device__ __forceinline__ void jacobi64_lds(float col[64], float& nrm,
                                             float* __restrict__ Wm,
                                             const int t,
                                             const int maxsweep, const float tolsq) {
  f32x2 cv[32];
#pragma unroll
  for (int j=0;j<32;j++) cv[j] = mk2(col[2*j], col[2*j+1]);
  {
#pragma unroll
    for (int jb=0;jb<16;jb++)
      *reinterpret_cast<f32x4*>(Wm + t*LDP + 4*jb) =
        (f32x4){cv[2*jb][0],cv[2*jb][1],cv[2*jb+1][0],cv[2*jb+1][1]};
    f32x2 n0=mk2(0.f,0.f), n1=mk2(0.f,0.f);
#pragma unroll
    for (int j=0;j<32;j+=2){ n0=pkf(cv[j],cv[j],n0); n1=pkf(cv[j+1],cv[j+1],n1); }
    nrm = (n0[0]+n0[1])+(n1[0]+n1[1]);
  }
#pragma unroll 1
  for (int sw=0; sw<maxsweep; ++sw){
    int anyrot=0;
#pragma unroll 1
    for (int m=1; m<64; ++m){
      const int pad = ((t ^ m) << 2);
      const unsigned pbase = lds_addr(Wm + (t ^ m)*LDP);
      float pn = bperm(pad, nrm);
      f32x4 q0,q1,q2,q3,q4,q5,q6,q7,q8,q9,q10,q11,q12,q13,q14,q15;
      asm volatile("ds_read_b128 %0, %1"             : "=v"(q0)  : "v"(pbase) : "memory");
      asm volatile("ds_read_b128 %0, %1 offset:16"   : "=v"(q1)  : "v"(pbase));
      asm volatile("ds_read_b128 %0, %1 offset:32"   : "=v"(q2)  : "v"(pbase));
      asm volatile("ds_read_b128 %0, %1 offset:48"   : "=v"(q3)  : "v"(pbase));
      asm volatile("ds_read_b128 %0, %1 offset:64"   : "=v"(q4)  : "v"(pbase));
      asm volatile("ds_read_b128 %0, %1 offset:80"   : "=v"(q5)  : "v"(pbase));
      asm volatile("ds_read_b128 %0, %1 offset:96"   : "=v"(q6)  : "v"(pbase));
      asm volatile("ds_read_b128 %0, %1 offset:112"  : "=v"(q7)  : "v"(pbase));
      asm volatile("ds_read_b128 %0, %1 offset:128"  : "=v"(q8)  : "v"(pbase));
      asm volatile("ds_read_b128 %0, %1 offset:144"  : "=v"(q9)  : "v"(pbase));
      asm volatile("ds_read_b128 %0, %1 offset:160"  : "=v"(q10) : "v"(pbase));
      asm volatile("ds_read_b128 %0, %1 offset:176"  : "=v"(q11) : "v"(pbase));
      asm volatile("ds_read_b128 %0, %1 offset:192"  : "=v"(q12) : "v"(pbase));
      asm volatile("ds_read_b128 %0, %1 offset:208"  : "=v"(q13) : "v"(pbase));
      asm volatile("ds_read_b128 %0, %1 offset:224"  : "=v"(q14) : "v"(pbase));
      asm volatile("ds_read_b128 %0, %1 offset:240"  : "=v"(q15) : "v"(pbase));
      asm volatile("s_waitcnt lgkmcnt(0)"
        : "+v"(q0),"+v"(q1),"+v"(q2),"+v"(q3),"+v"(q4),"+v"(q5),"+v"(q6),"+v"(q7));
      asm volatile(""
        : "+v"(q8),"+v"(q9),"+v"(q10),"+v"(q11),"+v"(q12),"+v"(q13),"+v"(q14),"+v"(q15));
      __builtin_amdgcn_sched_barrier(0);
      f32x2 a0=mk2(0.f,0.f), a1=mk2(0.f,0.f), a2=mk2(0.f,0.f), a3=mk2(0.f,0.f);
#define DOT2(JB,Q,X,Y) { f32x2 lo=mk2(Q[0],Q[1]), hi=mk2(Q[2],Q[3]); \
      X=pkf(cv[2*JB],lo,X); Y=pkf(cv[2*JB+1],hi,Y); }
      DOT2(0,q0,a0,a1)  DOT2(1,q1,a2,a3)  DOT2(2,q2,a0,a1)  DOT2(3,q3,a2,a3)
      DOT2(4,q4,a0,a1)  DOT2(5,q5,a2,a3)  DOT2(6,q6,a0,a1)  DOT2(7,q7,a2,a3)
      DOT2(8,q8,a0,a1)  DOT2(9,q9,a2,a3)  DOT2(10,q10,a0,a1) DOT2(11,q11,a2,a3)
      DOT2(12,q12,a0,a1) DOT2(13,q13,a2,a3) DOT2(14,q14,a0,a1) DOT2(15,q15,a2,a3)
#undef DOT2
      float apq = ((a0[0]+a0[1])+(a1[0]+a1[1])) + ((a2[0]+a2[1])+(a3[0]+a3[1]));
      const bool isP = t < (t ^ m);
      float app = isP ? nrm : pn;
      float aqq = isP ? pn : nrm;
      const bool rot = (apq*apq > tolsq*app*aqq);
      if (__any((int)rot)){
        float tau = (aqq - app) / (2.0f*apq);
        float tt  = 1.0f / (fabsf(tau) + sqrtf(fmaf(tau,tau,1.0f)));
        tt = (tau < 0.0f) ? -tt : tt;
        float cc = rsqrtf(fmaf(tt,tt,1.0f));
        float ss = cc*tt;
        float ccv = rot ? cc : 1.0f;
        float sgv = rot ? (isP ? -ss : ss) : 0.0f;
        const f32x2 c2=mk2(ccv,ccv), s2=mk2(sgv,sgv);
#define ROT2(JB,Q) { f32x2 lo=mk2(Q[0],Q[1]), hi=mk2(Q[2],Q[3]); \
        cv[2*JB]=pkf(c2,cv[2*JB],s2*lo); cv[2*JB+1]=pkf(c2,cv[2*JB+1],s2*hi); }
        ROT2(0,q0) ROT2(1,q1) ROT2(2,q2) ROT2(3,q3)
        ROT2(4,q4) ROT2(5,q5) ROT2(6,q6) ROT2(7,q7)
        ROT2(8,q8) ROT2(9,q9) ROT2(10,q10) ROT2(11,q11)
        ROT2(12,q12) ROT2(13,q13) ROT2(14,q14) ROT2(15,q15)
#undef ROT2
        float tq = tt*apq;
        nrm += rot ? (isP ? -tq : tq) : 0.0f;
        if (rot){
#pragma unroll
          for (int jb=0;jb<16;jb++)
            *reinterpret_cast<f32x4*>(Wm + t*LDP + 4*jb) =
              (f32x4){cv[2*jb][0],cv[2*jb][1],cv[2*jb+1][0],cv[2*jb+1][1]};
        }
        anyrot = 1;
      }
    }
    if (!__any(anyrot)) break;
  }
  {
    f32x2 n0=mk2(0.f,0.f), n1=mk2(0.f,0.f);
#pragma unroll
    for (int j=0;j<32;j+=2){ n0=pkf(cv[j],cv[j],n0); n1=pkf(cv[j+1],cv[j+1],n1); }
    nrm = (n0[0]+n0[1])+(n1[0]+n1[1]);
  }
#pragma unroll
  for (int j=0;j<32;j++){ col[2*j]=cv[j][0]; col[2*j+1]=cv[j][1]; }
}

// =====================================================================
// LDS-free congruence: col = (M * Xb * M^T) column t = M * (Xb * m_t).
// z-pass packed (contiguous uniform xr + per-lane mrow); col-update
// stays scalar (stride-64 uniform operands don't pack cleanly).
// =====================================================================
__device__ __forceinline__ void cong_cols(const float* __restrict__ Xb,
                                          const float* __restrict__ M,
                                          float col[64], const int t){
  f32x2 mv[32];
#pragma unroll
  for (int j=0;j<16;j++){
    float4 v = *reinterpret_cast<const float4*>(M + t*64 + 4*j);
    mv[2*j]   = mk2(v.x, v.y);
    mv[2*j+1] = mk2(v.z, v.w);
  }
#pragma unroll
  for (int i=0;i<64;i++) col[i]=0.f;
#pragma unroll 1
  for (int kb=0;kb<16;kb++){
    const float* xr = Xb + kb*256;
    f32x2 z0v=mk2(0.f,0.f), z1v=mk2(0.f,0.f), z2v=mk2(0.f,0.f), z3v=mk2(0.f,0.f);
#pragma unroll
    for (int jj=0;jj<32;jj++){
      f32x2 m2 = mv[jj];
      z0v = pkf(mk2(xr[2*jj],     xr[2*jj+1]),     m2, z0v);
      z1v = pkf(mk2(xr[64+2*jj],  xr[64+2*jj+1]),  m2, z1v);
      z2v = pkf(mk2(xr[128+2*jj], xr[128+2*jj+1]), m2, z2v);
      z3v = pkf(mk2(xr[192+2*jj], xr[192+2*jj+1]), m2, z3v);
    }
    float z0=z0v[0]+z0v[1], z1=z1v[0]+z1v[1], z2=z2v[0]+z2v[1], z3=z3v[0]+z3v[1];
    const float* mc = M + 4*kb;
#pragma unroll
    for (int i=0;i<64;i++){
      float c = col[i];
      c = fmaf(mc[i*64+0], z0, c);
      c = fmaf(mc[i*64+1], z1, c);
      c = fmaf(mc[i*64+2], z2, c);
      c = fmaf(mc[i*64+3], z3, c);
      col[i] = c;
    }
  }
}

// ================= K1: batch mean =================
__global__ __launch_bounds__(256) void k_mean(const float* __restrict__ X, float* __restrict__ meanAcc){
  const int tid=threadIdx.x; const int blk=blockIdx.x;
  float acc[16];
#pragma unroll
  for (int j=0;j<16;j++) acc[j]=0.f;
  const float* p = X + (size_t)blk*32*4096;
  for (int b2=0;b2<32;b2++){
#pragma unroll
    for (int j=0;j<16;j++) acc[j] += p[(size_t)b2*4096 + tid + 256*j];
  }
#pragma unroll
  for (int j=0;j<16;j++) atomicAdd(&meanAcc[tid+256*j], acc[j]*(1.0f/4096.0f));
}

// ================= 256-thread LDS matmul (col-major, stride LD2) =================
template<int MODE>
__device__ __forceinline__ void mmc256(float* __restrict__ dst, const float* __restrict__ A,
                                       const float* __restrict__ B, const float p0){
  const int tid=threadIdx.x; const int t=tid&63; const int i0=(tid>>6)*16;
  float acc[16];
#pragma unroll
  for (int j=0;j<16;j++) acc[j]=0.f;
#pragma unroll 4
  for (int k=0;k<64;k++){
    float bk = B[t*LD2+k];
#pragma unroll
    for (int j=0;j<16;j++) acc[j] = fmaf(A[k*LD2+i0+j], bk, acc[j]);
  }
  __syncthreads();
#pragma unroll
  for (int j=0;j<16;j++){
    int i=i0+j;
    float v=acc[j];
    if (MODE==1) v*=0.5f;
    if (MODE==2) v = ((i==t)?3.0f:0.0f) - v;
    if (MODE==3) v = v + ((i==t)?p0:0.0f);
    dst[t*LD2+i]=v;
  }
  __syncthreads();
}

__device__ __forceinline__ void chol_lds(float* __restrict__ C, const int tid, const int t, const int g){
  for (int j=0;j<64;j++){
    if (tid<64){
      float ljj = sqrtf(C[j*LD2+j]);
      float rinv = 1.0f/ljj;
      if (tid>=j) C[j*LD2+tid] = (tid==j)? ljj : C[j*LD2+tid]*rinv;
    }
    __syncthreads();
    for (int c=j+1+g; c<64; c+=4){
      float ljc = C[j*LD2+c];
      if (t>=c) C[c*LD2+t] -= C[j*LD2+t]*ljc;
    }
    __syncthreads();
  }
}

// ================= K2: Ms = mean^{1/2}, Mis = mean^{-1/2} via Newton-Schulz ====
__global__ __launch_bounds__(256) void k_sqrtmean(const float* __restrict__ meanw,
                                                  float* __restrict__ Msg, float* __restrict__ Misg){
  __shared__ float bufY[64*LD2], bufZ[64*LD2], bufT[64*LD2];
  const int tid=threadIdx.x;
  float tr=0.f;
  for (int k=0;k<64;k++) tr += meanw[k*65];
  const float alpha = 64.0f/tr;
  for (int e=tid; e<4096; e+=256){
    int r=e>>6, c=e&63;
    bufY[c*LD2+r] = alpha*meanw[e];
    bufZ[c*LD2+r] = (r==c)?1.0f:0.0f;
  }
  __syncthreads();
  float *pY=bufY, *pZ=bufZ, *pT=bufT;
  for (int it=0; it<5; ++it){
    mmc256<2>(pT, pZ, pY, 0.f);   // T = 3I - Z*Y
    mmc256<1>(pZ, pT, pZ, 0.f);   // Z' = 0.5*T*Z
    mmc256<1>(pT, pY, pT, 0.f);   // Y' = 0.5*Y*T
    float* tm=pY; pY=pT; pT=tm;
  }
  const float sa = sqrtf(alpha);
  const float isa = 1.0f/sa;
  for (int e=tid; e<4096; e+=256){
    int r=e>>6, c=e&63;
    Msg[e]  = pY[c*LD2+r]*isa;
    Misg[e] = pZ[c*LD2+r]*sa;
  }
}

// ================= K3: accumulate log(Mis X Mis) into slots =================
// Phase-1 (1e-7, 6) = R14-passing config. Reconstruction loop packed.
template<bool STOREQ>
__global__ __launch_bounds__(64,2) void k_logaccum(const float* __restrict__ X,
                                                   const float* __restrict__ Mis,
                                                   float* __restrict__ slots,
                                                   float* __restrict__ Qs,
                                                   float* __restrict__ Ls){
  __shared__ __align__(16) float Wm[64*LDP];
  __shared__ float wcoef[64];
  const int t=threadIdx.x & 63; const int b=blockIdx.x;
  float col[64]; float nrm;
  cong_cols(X + (size_t)b*4096, Mis, col, t);
  jacobi64_lds(col, nrm, Wm, t, 6, 1e-7f);
  if (STOREQ){
#pragma unroll
    for (int j=0;j<16;j++)
      *reinterpret_cast<float4*>(Qs + (size_t)b*4096 + t*64 + 4*j) =
          make_float4(col[4*j],col[4*j+1],col[4*j+2],col[4*j+3]);
    Ls[(size_t)b*64+t] = nrm;
  }
  wcoef[t] = 0.5f*logf(nrm)/nrm;
  f32x2 accv[32];
#pragma unroll
  for (int i=0;i<32;i++) accv[i]=mk2(0.f,0.f);
#pragma unroll 1
  for (int k=0;k<64;k++){
    float f = wcoef[k]*Wm[k*LDP+t];
    f32x2 fv = mk2(f,f);
#pragma unroll
    for (int jj=0;jj<16;jj++){
      float4 a = *reinterpret_cast<const float4*>(&Wm[k*LDP+4*jj]);
      accv[2*jj]   = pkf(mk2(a.x,a.y), fv, accv[2*jj]);
      accv[2*jj+1] = pkf(mk2(a.z,a.w), fv, accv[2*jj+1]);
    }
  }
  float* dst = slots + (size_t)(b & (NSLOTS-1))*4096;
#pragma unroll
  for (int p=0;p<32;p++){
    atomicAdd(&dst[(2*p)*64+t],   accv[p][0]);
    atomicAdd(&dst[(2*p+1)*64+t], accv[p][1]);
  }
}

// ================= K4: exp(tang), batch_mean, chol, Linv, Lb, C=Linv*Ms ======
__global__ __launch_bounds__(256) void k_mid(const float* __restrict__ slots,
                                             const float* __restrict__ Msg,
                                             const float* __restrict__ bias,
                                             float* __restrict__ Linvg, float* __restrict__ Lbg,
                                             float* __restrict__ Cg){
  __shared__ float b1[64*LD2], b2[64*LD2], b3[64*LD2];
  const int tid=threadIdx.x; const int t=tid&63; const int g=tid>>6;
  for (int e=tid; e<4096; e+=256){
    float s=0.f;
    for (int sl=0; sl<NSLOTS; ++sl) s += slots[(size_t)sl*4096+e];
    b1[(e&63)*LD2+(e>>6)] = s * (1.0f/(4096.0f*16.0f));
  }
  __syncthreads();
  for (int e=tid; e<4096; e+=256){
    int r=e>>6, c=e&63;
    b2[c*LD2+r] = (1.0f/40320.0f)*b1[c*LD2+r] + ((r==c)?(1.0f/5040.0f):0.0f);
  }
  __syncthreads();
  float *pR=b2, *pT=b3;
  const float cj0=1.f/720.f, cj1=1.f/120.f, cj2=1.f/24.f, cj3=1.f/6.f, cj4=0.5f, cj5=1.f, cj6=1.f;
  mmc256<3>(pT,b1,pR,cj0); { float* tm=pR; pR=pT; pT=tm; }
  mmc256<3>(pT,b1,pR,cj1); { float* tm=pR; pR=pT; pT=tm; }
  mmc256<3>(pT,b1,pR,cj2); { float* tm=pR; pR=pT; pT=tm; }
  mmc256<3>(pT,b1,pR,cj3); { float* tm=pR; pR=pT; pT=tm; }
  mmc256<3>(pT,b1,pR,cj4); { float* tm=pR; pR=pT; pT=tm; }
  mmc256<3>(pT,b1,pR,cj5); { float* tm=pR; pR=pT; pT=tm; }
  mmc256<3>(pT,b1,pR,cj6); { float* tm=pR; pR=pT; pT=tm; }
  for (int q=0;q<4;q++){ mmc256<0>(pT, pR, pR, 0.f); float* tm=pR; pR=pT; pT=tm; }
  for (int e=tid; e<4096; e+=256) b1[(e&63)*LD2+(e>>6)] = Msg[e];
  __syncthreads();
  mmc256<0>(pT, b1, pR, 0.f);   // T = Ms*E
  mmc256<0>(pR, pT, b1, 0.f);   // bm = T*Ms
  chol_lds(pR, tid, t, g);      // pR holds L (lower, col-major)
  if (tid<64){
    const int c=tid;
    for (int k=0;k<64;k++) pT[c*LD2+k]=0.f;
    for (int i=0;i<64;i++){
      float s = (i==c)?1.0f:0.0f;
      for (int k=0;k<i;k++) s -= pR[k*LD2+i]*pT[c*LD2+k];
      pT[c*LD2+i] = s / pR[i*LD2+i];
    }
  }
  __syncthreads();
  if (tid<64){
    const int c=tid;
    for (int i=0;i<64;i++) Linvg[i*64+c] = pT[c*LD2+i];
  }
  // C = Linv * Ms  (pT holds Linv col-major, b1 holds Ms col-major)
  mmc256<0>(pR, pT, b1, 0.f);   // pR[t*LD2+i] = C[i][t]
  for (int e=tid; e<4096; e+=256) Cg[e] = pR[(e&63)*LD2+(e>>6)];  // row-major
  for (int e=tid; e<4096; e+=256) b1[(e&63)*LD2+(e>>6)] = bias[e];
  __syncthreads();
  chol_lds(b1, tid, t, g);
  if (tid<64){
    const int c=tid;
    for (int i=0;i<64;i++) Lbg[i*64+c] = (c<=i)? b1[c*LD2+i] : 0.0f;
  }
}

// ================= K5: Xc eig via warm start, var accumulation =================
// WARM: W0 col t = C * (nrm^{-1/4} w_t) = C * (lam^{1/2} q_t).
template<bool WARM>
__global__ __launch_bounds__(64,2) void k_center(const float* __restrict__ X,
                                                 const float* __restrict__ Linv,
                                                 const float* __restrict__ Cg,
                                                 float* __restrict__ varAcc,
                                                 float* __restrict__ Qs, float* __restrict__ Ls){
  __shared__ __align__(16) float Wm[64*LDP];
  const int t=threadIdx.x & 63; const int b=blockIdx.x;
  float col[64]; float nrm;
  if (WARM){
    const float s = rsqrtf(sqrtf(Ls[(size_t)b*64+t]));   // nrm^{-1/4}
    const float* q1 = Qs + (size_t)b*4096 + t*64;
#pragma unroll
    for (int i=0;i<64;i++) col[i]=0.f;
#pragma unroll 1
    for (int kb=0;kb<16;kb++){
      float4 v = *reinterpret_cast<const float4*>(q1 + 4*kb);
      float x0=v.x*s, x1=v.y*s, x2=v.z*s, x3=v.w*s;
      const float* cc = Cg + 4*kb;
#pragma unroll
      for (int i=0;i<64;i++){
        float c = col[i];
        c = fmaf(cc[i*64+0], x0, c);
        c = fmaf(cc[i*64+1], x1, c);
        c = fmaf(cc[i*64+2], x2, c);
        c = fmaf(cc[i*64+3], x3, c);
        col[i] = c;
      }
    }
    jacobi64_lds(col, nrm, Wm, t, 8, 1e-10f);
  } else {
    cong_cols(X + (size_t)b*4096, Linv, col, t);
    jacobi64_lds(col, nrm, Wm, t, 10, 1e-10f);
  }
  float ll = 0.5f*logf(nrm);
  float f2 = ll*ll;
#pragma unroll
  for (int off=1; off<64; off<<=1) f2 += __shfl_xor(f2, off, 64);
  if (t==0) atomicAdd(varAcc, f2);
  if (WARM){
#pragma unroll
    for (int j=0;j<16;j++)
      *reinterpret_cast<float4*>(Qs + (size_t)b*4096 + t*64 + 4*j) =
          make_float4(col[4*j],col[4*j+1],col[4*j+2],col[4*j+3]);
    Ls[(size_t)b*64+t] = nrm;
  }
}

// ================= K7: Xs = sum lam^f q q^T ; out = Lb Xs Lb^T =================
template<bool LOADW>
__global__ __launch_bounds__(64,2) void k_out(const float* __restrict__ X,
                                              const float* __restrict__ Linv,
                                              const float* __restrict__ Qs,
                                              const float* __restrict__ Ls,
                                              const float* __restrict__ Lb,
                                              const float* __restrict__ varAcc,
                                              const float* __restrict__ shift,
                                              float* __restrict__ out){
  __shared__ __align__(16) float Wm[64*LDP];
  __shared__ float wcoef[64];
  const int t=threadIdx.x & 63; const int b=blockIdx.x;
  float col[64]; float nrm;
  if (LOADW){
#pragma unroll
    for (int j=0;j<16;j++){
      float4 v = *reinterpret_cast<const float4*>(Qs + (size_t)b*4096 + t*64 + 4*j);
      col[4*j+0]=v.x; col[4*j+1]=v.y; col[4*j+2]=v.z; col[4*j+3]=v.w;
    }
    nrm = Ls[(size_t)b*64+t];
#pragma unroll
    for (int j=0;j<16;j++)
      *reinterpret_cast<float4*>(&Wm[t*LDP+4*j]) = make_float4(col[4*j],col[4*j+1],col[4*j+2],col[4*j+3]);
  } else {
    cong_cols(X + (size_t)b*4096, Linv, col, t);
    jacobi64_lds(col, nrm, Wm, t, 10, 1e-10f);
  }
  __syncthreads();
  const float var = varAcc[0] * (1.0f/4096.0f);
  const float factor = shift[0] * rsqrtf(var + 1e-5f);
  wcoef[t] = expf((factor-2.0f)*0.5f*logf(nrm));   // lam^{f-2}
  __syncthreads();
  f32x2 accv[32];
#pragma unroll
  for (int i=0;i<32;i++) accv[i]=mk2(0.f,0.f);
#pragma unroll 1
  for (int k=0;k<64;k++){
    float f = wcoef[k]*Wm[k*LDP+t];
    f32x2 fv = mk2(f,f);
#pragma unroll
    for (int jj=0;jj<16;jj++){
      float4 a = *reinterpret_cast<const float4*>(&Wm[k*LDP+4*jj]);
      accv[2*jj]   = pkf(mk2(a.x,a.y), fv, accv[2*jj]);
      accv[2*jj+1] = pkf(mk2(a.z,a.w), fv, accv[2*jj+1]);
    }
  }
  __syncthreads();
  // T2 = Lb * Xs (col-major into Wm); Lb rows uniform contiguous -> packed
#pragma unroll 2
  for (int i=0;i<64;i++){
    f32x2 s2=mk2(0.f,0.f), s3=mk2(0.f,0.f);
#pragma unroll
    for (int kk=0;kk<32;kk+=2){
      s2 = pkf(mk2(Lb[i*64+2*kk],   Lb[i*64+2*kk+1]), accv[kk],   s2);
      s3 = pkf(mk2(Lb[i*64+2*kk+2], Lb[i*64+2*kk+3]), accv[kk+1], s3);
    }
    Wm[t*LDP+i]=(s2[0]+s2[1])+(s3[0]+s3[1]);
  }
  f32x2 ov[32];
#pragma unroll
  for (int i=0;i<32;i++) ov[i]=mk2(0.f,0.f);
#pragma unroll 1
  for (int k=0;k<64;k++){
    float bk = Lb[t*64+k];
    f32x2 bkv = mk2(bk,bk);
#pragma unroll
    for (int jj=0;jj<16;jj++){
      float4 a = *reinterpret_cast<const float4*>(&Wm[k*LDP+4*jj]);
      ov[2*jj]   = pkf(mk2(a.x,a.y), bkv, ov[2*jj]);
      ov[2*jj+1] = pkf(mk2(a.z,a.w), bkv, ov[2*jj+1]);
    }
  }
  float* ob = out + (size_t)b*4096;
#pragma unroll
  for (int p=0;p<32;p++){
    ob[(2*p)*64+t]   = ov[p][0];
    ob[(2*p+1)*64+t] = ov[p][1];
  }
}

// =====================================================================
extern "C" void kernel_launch(void* const* d_in, const int* in_sizes, int n_in,
                              void* d_out, int out_size, void* d_ws, size_t ws_size,
                              hipStream_t stream){
  (void)in_sizes; (void)n_in; (void)out_size;
  const float* X     = (const float*)d_in[0];
  const float* bias  = (const float*)d_in[1];
  const float* shift = (const float*)d_in[2];
  float* out = (float*)d_out;
  float* ws  = (float*)d_ws;

  (void)hipMemsetAsync(d_ws, 0, (size_t)WS_ZERO_FLOATS*sizeof(float), stream);
  k_mean<<<128,256,0,stream>>>(X, ws+OFF_MEAN);
  k_sqrtmean<<<1,256,0,stream>>>(ws+OFF_MEAN, ws+OFF_MS, ws+OFF_MIS);

  const bool big = ws_size >= (size_t)WS_FULL*sizeof(float);
  if (big){
    k_logaccum<true><<<NB,64,0,stream>>>(X, ws+OFF_MIS, ws+OFF_SLOTS, ws+OFF_Q, ws+OFF_LAM);
    k_mid<<<1,256,0,stream>>>(ws+OFF_SLOTS, ws+OFF_MS, bias, ws+OFF_LINV, ws+OFF_LB, ws+OFF_C);
    k_center<true><<<NB,64,0,stream>>>(X, ws+OFF_LINV, ws+OFF_C, ws+OFF_VAR, ws+OFF_Q, ws+OFF_LAM);
    k_out<true><<<NB,64,0,stream>>>(X, ws+OFF_LINV, ws+OFF_Q, ws+OFF_LAM, ws+OFF_LB, ws+OFF_VAR, shift, out);
  } else {
    k_logaccum<false><<<NB,64,0,stream>>>(X, ws+OFF_MIS, ws+OFF_SLOTS, nullptr, nullptr);
    k_mid<<<1,256,0,stream>>>(ws+OFF_SLOTS, ws+OFF_MS, bias, ws+OFF_LINV, ws+OFF_LB, ws+OFF_C);
    k_center<false><<<NB,64,0,stream>>>(X, ws+OFF_LINV, nullptr, ws+OFF_VAR, nullptr, nullptr);
    k_out<false><<<NB,64,0,stream>>>(X, ws+OFF_LINV, nullptr, nullptr, ws+OFF_LB, ws+OFF_VAR, shift, out);
  }
}